// Round 1
// baseline (10586.375 us; speedup 1.0000x reference)
//
#include <hip/hip_runtime.h>
#include <math.h>

#define TT 1024
#define BB 8
#define DD 512
#define HH 8
#define HSZ 64
#define LL 6
#define FF4 2048

// ---------------- embed + positional encoding ----------------
__global__ __launch_bounds__(256) void k_embed(const int* __restrict__ code,
                                               const float* __restrict__ emb,
                                               float* __restrict__ x) {
  int idx = blockIdx.x * 256 + threadIdx.x;  // over B*T*D
  int c = idx & (DD - 1);
  int bt = idx >> 9;
  int t = bt & (TT - 1);
  int f = c >> 4, e = c & 15;
  int vv = code[bt * 32 + f];
  int i = c >> 1;
  float freq = expf((float)(2 * i) * (-9.210340371976184f / 512.f));
  float ang = (float)t * freq;
  float pe = (c & 1) ? cosf(ang) : sinf(ang);
  x[idx] = emb[vv * 16 + e] + pe;
}

// ---------------- layernorm: one wave per 512-wide row ----------------
__global__ __launch_bounds__(256) void k_ln(const float* __restrict__ x,
                                            float* __restrict__ y,
                                            const float* __restrict__ g,
                                            const float* __restrict__ b) {
  int wave = threadIdx.x >> 6, lane = threadIdx.x & 63;
  int row = blockIdx.x * 4 + wave;
  const float* xr = x + (size_t)row * DD;
  float v[8];
  float s = 0.f;
#pragma unroll
  for (int j = 0; j < 8; ++j) { v[j] = xr[lane + 64 * j]; s += v[j]; }
#pragma unroll
  for (int off = 32; off; off >>= 1) s += __shfl_down(s, off, 64);
  float mean = __shfl(s, 0, 64) * (1.f / DD);
  float qv = 0.f;
#pragma unroll
  for (int j = 0; j < 8; ++j) { float d = v[j] - mean; qv += d * d; }
#pragma unroll
  for (int off = 32; off; off >>= 1) qv += __shfl_down(qv, off, 64);
  float rs = rsqrtf(__shfl(qv, 0, 64) * (1.f / DD) + 1e-5f);
  float* yr = y + (size_t)row * DD;
#pragma unroll
  for (int j = 0; j < 8; ++j) {
    int c = lane + 64 * j;
    yr[c] = (v[j] - mean) * rs * g[c] + b[c];
  }
}

// ---------------- generic fp32 GEMM, 64x64 tile, 4x4 per thread ----------------
// B element (d, n) lives at  B[d*ldb + (n>>6)*hstride + (n&63)]
//   normal (K,N) matrix  : ldb=N,  hstride=64     -> d*N + n
//   (H,D,HS) qkv weights : ldb=64, hstride=D*HS   -> h*D*HS + d*64 + e
// out = [Cin +] act(acc + bias)
__global__ __launch_bounds__(256) void k_gemm(const float* __restrict__ A,
                                              const float* __restrict__ B,
                                              const float* __restrict__ Cin,
                                              float* __restrict__ Cout,
                                              const float* __restrict__ bias,
                                              int M, int N, int K,
                                              int ldb, int hstride, int dogelu) {
  __shared__ float As[64][17];
  __shared__ float Bs[16][68];
  int tx = threadIdx.x & 15, ty = threadIdx.x >> 4;
  int row0 = blockIdx.y * 64, col0 = blockIdx.x * 64;
  float acc[4][4] = {{0.f}};
  int hbase = (col0 >> 6) * hstride;
  int lr = threadIdx.x >> 2;
  int lk = (threadIdx.x & 3) << 2;
  int bk = threadIdx.x >> 4;
  int bj = (threadIdx.x & 15) << 2;
  for (int k0 = 0; k0 < K; k0 += 16) {
    float4 av = *(const float4*)(A + (size_t)(row0 + lr) * K + k0 + lk);
    float4 bv = *(const float4*)(B + (size_t)(k0 + bk) * ldb + hbase + bj);
    As[lr][lk + 0] = av.x; As[lr][lk + 1] = av.y;
    As[lr][lk + 2] = av.z; As[lr][lk + 3] = av.w;
    *(float4*)&Bs[bk][bj] = bv;  // row stride 272B -> 16B aligned
    __syncthreads();
#pragma unroll
    for (int kk = 0; kk < 16; ++kk) {
      float4 bq = *(const float4*)&Bs[kk][tx << 2];
      float a0 = As[(ty << 2) + 0][kk];
      float a1 = As[(ty << 2) + 1][kk];
      float a2 = As[(ty << 2) + 2][kk];
      float a3 = As[(ty << 2) + 3][kk];
      acc[0][0] += a0 * bq.x; acc[0][1] += a0 * bq.y; acc[0][2] += a0 * bq.z; acc[0][3] += a0 * bq.w;
      acc[1][0] += a1 * bq.x; acc[1][1] += a1 * bq.y; acc[1][2] += a1 * bq.z; acc[1][3] += a1 * bq.w;
      acc[2][0] += a2 * bq.x; acc[2][1] += a2 * bq.y; acc[2][2] += a2 * bq.z; acc[2][3] += a2 * bq.w;
      acc[3][0] += a3 * bq.x; acc[3][1] += a3 * bq.y; acc[3][2] += a3 * bq.z; acc[3][3] += a3 * bq.w;
    }
    __syncthreads();
  }
#pragma unroll
  for (int i = 0; i < 4; ++i) {
    int r = row0 + (ty << 2) + i;
    size_t rb = (size_t)r * N + col0 + (tx << 2);
#pragma unroll
    for (int j = 0; j < 4; ++j) {
      float val = acc[i][j];
      int cidx = col0 + (tx << 2) + j;
      if (bias) val += bias[cidx];
      if (dogelu) val = 0.5f * val * (1.f + erff(val * 0.70710678118f));
      if (Cin) val += Cin[rb + j];
      Cout[rb + j] = val;
    }
  }
}

// ---------------- flash-style masked attention ----------------
// q,k,v layout: [(b*T+t)*512 + h*64 + e]. One wave (64 threads) per
// (b, h, 64-query tile); each lane owns one query row. Online softmax.
__global__ __launch_bounds__(64) void k_attn(const float* __restrict__ q,
                                             const float* __restrict__ k,
                                             const float* __restrict__ v,
                                             const int* __restrict__ lengths,
                                             float* __restrict__ o) {
  __shared__ float Ks[64][68];
  __shared__ float Vs[64][68];
  int lane = threadIdx.x;
  int tile = blockIdx.x & 15;
  int bh = blockIdx.x >> 4;
  int b = bh >> 3, h = bh & 7;
  int t = tile * 64 + lane;
  int len = lengths[b];
  size_t rowbase = ((size_t)(b * TT + t)) * DD + h * HSZ;
  float4 qv[16];
  const float4* qp = (const float4*)(q + rowbase);
#pragma unroll
  for (int i = 0; i < 16; ++i) qv[i] = qp[i];
  float4 acc[16];
#pragma unroll
  for (int i = 0; i < 16; ++i) acc[i] = make_float4(0.f, 0.f, 0.f, 0.f);
  float mrun = -1e30f, lrun = 0.f;
  int nkt = (len + 63) >> 6;  // ceil(len/64) <= 16, so all loads stay in-bounds
  for (int kt = 0; kt < nkt; ++kt) {
    int s0 = kt * 64;
    int smax = min(64, len - s0);
    __syncthreads();
#pragma unroll
    for (int p = 0; p < 16; ++p) {
      int f = lane + 64 * p;  // 1024 float4 = 64 rows x 16
      int s = f >> 4, e4 = f & 15;
      size_t gb = ((size_t)(b * TT + s0 + s)) * DD + h * HSZ + (e4 << 2);
      *(float4*)&Ks[s][e4 << 2] = *(const float4*)(k + gb);
      *(float4*)&Vs[s][e4 << 2] = *(const float4*)(v + gb);
    }
    __syncthreads();
    for (int s = 0; s < smax; ++s) {
      const float4* kr = (const float4*)&Ks[s][0];
      float sc = 0.f;
#pragma unroll
      for (int i = 0; i < 16; ++i) {
        float4 kv4 = kr[i];
        sc += qv[i].x * kv4.x + qv[i].y * kv4.y + qv[i].z * kv4.z + qv[i].w * kv4.w;
      }
      sc *= 0.125f;  // HS^-0.5
      float mnew = fmaxf(mrun, sc);
      float p = __expf(sc - mnew);
      float corr = __expf(mrun - mnew);
      lrun = lrun * corr + p;
      const float4* vr = (const float4*)&Vs[s][0];
#pragma unroll
      for (int i = 0; i < 16; ++i) {
        float4 vv4 = vr[i];
        acc[i].x = acc[i].x * corr + p * vv4.x;
        acc[i].y = acc[i].y * corr + p * vv4.y;
        acc[i].z = acc[i].z * corr + p * vv4.z;
        acc[i].w = acc[i].w * corr + p * vv4.w;
      }
      mrun = mnew;
    }
  }
  float inv = (t < len) ? 1.f / lrun : 0.f;  // row mask zeroes padded queries
  float4* op = (float4*)(o + rowbase);
#pragma unroll
  for (int i = 0; i < 16; ++i) {
    float4 r;
    r.x = acc[i].x * inv; r.y = acc[i].y * inv;
    r.z = acc[i].z * inv; r.w = acc[i].w * inv;
    op[i] = r;
  }
}

// ---------------- attention pooling (per batch) ----------------
__global__ __launch_bounds__(256) void k_pool(const float* __restrict__ xn,
                                              const int* __restrict__ lengths,
                                              const float* __restrict__ attn_w,
                                              const float* __restrict__ attn_b,
                                              float* __restrict__ summary) {
  __shared__ __align__(16) float sw[DD];
  __shared__ float sc[TT];
  __shared__ float red[8];
  int tid = threadIdx.x, b = blockIdx.x;
  int len = lengths[b];
  for (int i = tid; i < DD; i += 256) sw[i] = attn_w[i];
  __syncthreads();
  const float* xb = xn + (size_t)b * TT * DD;
  float ab = attn_b[0];
  for (int t = tid; t < TT; t += 256) {
    const float4* xr = (const float4*)(xb + (size_t)t * DD);
    const float4* wr = (const float4*)sw;
    float s = 0.f;
    for (int d = 0; d < DD / 4; ++d) {
      float4 xv = xr[d], wv = wr[d];
      s += xv.x * wv.x + xv.y * wv.y + xv.z * wv.z + xv.w * wv.w;
    }
    sc[t] = s + ab;
  }
  __syncthreads();
  float m = -1e30f;
  for (int t = tid; t < len; t += 256) m = fmaxf(m, sc[t]);
#pragma unroll
  for (int off = 32; off; off >>= 1) m = fmaxf(m, __shfl_down(m, off, 64));
  if ((tid & 63) == 0) red[tid >> 6] = m;
  __syncthreads();
  m = fmaxf(fmaxf(red[0], red[1]), fmaxf(red[2], red[3]));
  float ssum = 0.f;
  for (int t = tid; t < len; t += 256) ssum += __expf(sc[t] - m);
#pragma unroll
  for (int off = 32; off; off >>= 1) ssum += __shfl_down(ssum, off, 64);
  if ((tid & 63) == 0) red[4 + (tid >> 6)] = ssum;
  __syncthreads();
  float inv = 1.f / (red[4] + red[5] + red[6] + red[7]);
  __syncthreads();
  for (int t = tid; t < TT; t += 256) sc[t] = (t < len) ? __expf(sc[t] - m) * inv : 0.f;
  __syncthreads();
  for (int d = tid; d < DD; d += 256) {
    float acc = 0.f;
    for (int t = 0; t < TT; ++t) acc += sc[t] * xb[(size_t)t * DD + d];
    summary[b * DD + d] = acc;
  }
}

// ---------------- classification head ----------------
__global__ __launch_bounds__(64) void k_head(const float* __restrict__ summary,
                                             const float* __restrict__ head_w,
                                             const float* __restrict__ head_b,
                                             float* __restrict__ out) {
  int b = blockIdx.x, j = threadIdx.x;
  if (j < 49) {
    float s = head_b[j];
    for (int d = 0; d < DD; ++d) s += summary[b * DD + d] * head_w[d * 49 + j];
    out[b * 49 + j] = s;
  }
}

extern "C" void kernel_launch(void* const* d_in, const int* in_sizes, int n_in,
                              void* d_out, int out_size, void* d_ws, size_t ws_size,
                              hipStream_t stream) {
  const int* code = (const int*)d_in[0];
  const int* lengths = (const int*)d_in[1];
  const float* emb = (const float*)d_in[2];
  const float* Wq = (const float*)d_in[3];
  const float* Wk = (const float*)d_in[4];
  const float* Wv = (const float*)d_in[5];
  const float* Wo = (const float*)d_in[6];
  const float* bo = (const float*)d_in[7];
  const float* W1 = (const float*)d_in[8];
  const float* b1 = (const float*)d_in[9];
  const float* W2 = (const float*)d_in[10];
  const float* b2 = (const float*)d_in[11];
  const float* ln1_g = (const float*)d_in[12];
  const float* ln1_b = (const float*)d_in[13];
  const float* ln2_g = (const float*)d_in[14];
  const float* ln2_b = (const float*)d_in[15];
  const float* lnf_g = (const float*)d_in[16];
  const float* lnf_b = (const float*)d_in[17];
  const float* attn_w = (const float*)d_in[18];
  const float* attn_b = (const float*)d_in[19];
  const float* head_w = (const float*)d_in[20];
  const float* head_b = (const float*)d_in[21];
  float* out = (float*)d_out;

  const size_t NTOK = (size_t)BB * TT;  // 8192
  float* ws = (float*)d_ws;
  float* x = ws;                 // 8192*512
  float* xn = x + NTOK * DD;     // LN output; reused as attention output o
  float* q = xn + NTOK * DD;
  float* k = q + NTOK * DD;
  float* v = k + NTOK * DD;
  float* h1 = v + NTOK * DD;     // 4096*2048 (FFN chunked x2) -> total ws ~117MB
  float* summary = q;            // 8*512, q dead by then

  k_embed<<<dim3((unsigned)((NTOK * DD) / 256)), dim3(256), 0, stream>>>(code, emb, x);

  for (int l = 0; l < LL; ++l) {
    k_ln<<<dim3(NTOK / 4), dim3(256), 0, stream>>>(x, xn, ln1_g + l * DD, ln1_b + l * DD);
    const float* wq = Wq + (size_t)l * HH * DD * HSZ;
    const float* wk = Wk + (size_t)l * HH * DD * HSZ;
    const float* wv = Wv + (size_t)l * HH * DD * HSZ;
    k_gemm<<<dim3(DD / 64, NTOK / 64), dim3(256), 0, stream>>>(
        xn, wq, nullptr, q, nullptr, (int)NTOK, DD, DD, HSZ, DD * HSZ, 0);
    k_gemm<<<dim3(DD / 64, NTOK / 64), dim3(256), 0, stream>>>(
        xn, wk, nullptr, k, nullptr, (int)NTOK, DD, DD, HSZ, DD * HSZ, 0);
    k_gemm<<<dim3(DD / 64, NTOK / 64), dim3(256), 0, stream>>>(
        xn, wv, nullptr, v, nullptr, (int)NTOK, DD, DD, HSZ, DD * HSZ, 0);
    k_attn<<<dim3(BB * HH * (TT / 64)), dim3(64), 0, stream>>>(q, k, v, lengths, xn);
    k_gemm<<<dim3(DD / 64, NTOK / 64), dim3(256), 0, stream>>>(
        xn, Wo + (size_t)l * DD * DD, x, x, bo + l * DD, (int)NTOK, DD, DD, DD, 64, 0);
    k_ln<<<dim3(NTOK / 4), dim3(256), 0, stream>>>(x, xn, ln2_g + l * DD, ln2_b + l * DD);
    for (int ch = 0; ch < 2; ++ch) {
      const float* a = xn + (size_t)ch * 4096 * DD;
      float* xc = x + (size_t)ch * 4096 * DD;
      k_gemm<<<dim3(FF4 / 64, 4096 / 64), dim3(256), 0, stream>>>(
          a, W1 + (size_t)l * DD * FF4, nullptr, h1, b1 + l * FF4, 4096, FF4, DD, FF4, 64, 1);
      k_gemm<<<dim3(DD / 64, 4096 / 64), dim3(256), 0, stream>>>(
          h1, W2 + (size_t)l * FF4 * DD, xc, xc, b2 + l * DD, 4096, DD, FF4, DD, 64, 0);
    }
  }
  k_ln<<<dim3(NTOK / 4), dim3(256), 0, stream>>>(x, xn, lnf_g, lnf_b);
  k_pool<<<dim3(BB), dim3(256), 0, stream>>>(xn, lengths, attn_w, attn_b, summary);
  k_head<<<dim3(BB), dim3(64), 0, stream>>>(summary, head_w, head_b, out);
}

// Round 2
// 6585.242 us; speedup vs baseline: 1.6076x; 1.6076x over previous
//
#include <hip/hip_runtime.h>
#include <math.h>

#define TT 1024
#define BB 8
#define DD 512
#define HH 8
#define HSZ 64
#define LL 6
#define FF4 2048

typedef __attribute__((ext_vector_type(8))) short short8;
typedef __attribute__((ext_vector_type(4))) float floatx4;
typedef unsigned short ushort_t;
typedef unsigned int uint_t;

__device__ __forceinline__ ushort_t f2bf(float f) {
  uint_t u = __float_as_uint(f);
  u += 0x7fff + ((u >> 16) & 1);  // RNE
  return (ushort_t)(u >> 16);
}
__device__ __forceinline__ float bf2f(ushort_t h) {
  return __uint_as_float(((uint_t)h) << 16);
}

__device__ __forceinline__ void gload16(const void* g, void* l) {
  __builtin_amdgcn_global_load_lds((const __attribute__((address_space(1))) void*)g,
                                   (__attribute__((address_space(3))) void*)l, 16, 0, 0);
}

// ---------------- embed + positional encoding ----------------
__global__ __launch_bounds__(256) void k_embed(const int* __restrict__ code,
                                               const float* __restrict__ emb,
                                               float* __restrict__ x) {
  int idx = blockIdx.x * 256 + threadIdx.x;  // over B*T*D
  int c = idx & (DD - 1);
  int bt = idx >> 9;
  int t = bt & (TT - 1);
  int f = c >> 4, e = c & 15;
  int vv = code[bt * 32 + f];
  int i = c >> 1;
  float freq = expf((float)(2 * i) * (-9.210340371976184f / 512.f));
  float ang = (float)t * freq;
  float pe = (c & 1) ? cosf(ang) : sinf(ang);
  x[idx] = emb[vv * 16 + e] + pe;
}

// ---------------- layernorm: one wave per 512-wide row, fp32 in, bf16 (or fp32) out ----------------
__global__ __launch_bounds__(256) void k_ln(const float* __restrict__ x,
                                            ushort_t* __restrict__ yB,
                                            float* __restrict__ yF,
                                            const float* __restrict__ g,
                                            const float* __restrict__ b) {
  int wave = threadIdx.x >> 6, lane = threadIdx.x & 63;
  int row = blockIdx.x * 4 + wave;
  const float* xr = x + (size_t)row * DD;
  float v[8];
  float s = 0.f;
#pragma unroll
  for (int j = 0; j < 8; ++j) { v[j] = xr[lane + 64 * j]; s += v[j]; }
#pragma unroll
  for (int off = 32; off; off >>= 1) s += __shfl_down(s, off, 64);
  float mean = __shfl(s, 0, 64) * (1.f / DD);
  float qv = 0.f;
#pragma unroll
  for (int j = 0; j < 8; ++j) { float d = v[j] - mean; qv += d * d; }
#pragma unroll
  for (int off = 32; off; off >>= 1) qv += __shfl_down(qv, off, 64);
  float rs = rsqrtf(__shfl(qv, 0, 64) * (1.f / DD) + 1e-5f);
#pragma unroll
  for (int j = 0; j < 8; ++j) {
    int c = lane + 64 * j;
    float val = (v[j] - mean) * rs * g[c] + b[c];
    if (yB) yB[(size_t)row * DD + c] = f2bf(val);
    else    yF[(size_t)row * DD + c] = val;
  }
}

// ---------------- fp32 -> bf16 transposed weight prep ----------------
// in: [K][Nin] fp32 (matrix mz at in + mz*in_ms)
// out: [n][out_ld] bf16 at out + (mz/nh)*os_l + (mz%nh)*os_h
__global__ __launch_bounds__(256) void k_transpose(const float* __restrict__ in,
                                                   ushort_t* __restrict__ out,
                                                   int Nin, long in_ms, int nh,
                                                   long os_l, long os_h, int out_ld) {
  __shared__ float t4[64][65];
  int mz = blockIdx.z;
  const float* ip = in + (size_t)mz * in_ms;
  ushort_t* op = out + (size_t)(mz / nh) * os_l + (size_t)(mz % nh) * os_h;
  int k0 = blockIdx.x * 64, n0 = blockIdx.y * 64;
  int c = threadIdx.x & 63, r0 = threadIdx.x >> 6;
#pragma unroll
  for (int i = 0; i < 16; ++i) {
    int r = r0 * 16 + i;
    t4[r][c] = ip[(size_t)(k0 + r) * Nin + n0 + c];
  }
  __syncthreads();
#pragma unroll
  for (int i = 0; i < 16; ++i) {
    int n = r0 * 16 + i;
    op[(size_t)(n0 + n) * out_ld + k0 + c] = f2bf(t4[c][n]);
  }
}

// ---------------- bf16 MFMA GEMM (m97 structure) ----------------
// C[M,N] = A[M,K] (bf16, row-major) x Bt[N,K] (bf16, pre-transposed)
// 128x128 tile, BK=32, 4 waves (2x2 of 64x64), 16x16x32 MFMA, global_load_lds staging.
// LDS layout (16B slots): A slot(kc,m) = A[row0+m][k0+kc*8 ..+8], kc=0..3, m=0..127.
//                          B slot(kc,n) likewise at +4096 shorts.
// epilogue: val = acc (+bias[col]) (gelu) (+resid[idx]); write fp32 or bf16.
__global__ __launch_bounds__(256) void k_gemm(const ushort_t* __restrict__ A,
                                              const ushort_t* __restrict__ Bt,
                                              const float* __restrict__ resid,
                                              const float* __restrict__ bias,
                                              float* __restrict__ outF,
                                              ushort_t* __restrict__ outB,
                                              int M, int N, int K, int dogelu) {
  __shared__ short lds[8192];
  const int tid = threadIdx.x;
  const int w = tid >> 6, lane = tid & 63;
  const int quad = lane >> 4, l16 = lane & 15;
  const int wm = w >> 1, wn = w & 1;
  const int row0 = blockIdx.y * 128, col0 = blockIdx.x * 128;
  const short* Ag = (const short*)A + (size_t)(row0 + lane) * K + w * 8;  // wave w stages kc=w
  const short* Bg = (const short*)Bt + (size_t)(col0 + lane) * K + w * 8;
  short* lA = &lds[w * 1024];         // slots w*128 .. (+128), 8 shorts each
  short* lB = &lds[4096 + w * 1024];
  floatx4 acc[4][4] = {};
  const int aoff = (quad * 128 + wm * 64 + l16) * 8;         // A frag: m=l16, k=quad*8+j
  const int boff = 4096 + (quad * 128 + wn * 64 + l16) * 8;  // B frag: n=l16, k=quad*8+j
  for (int k0 = 0; k0 < K; k0 += 32) {
    gload16(Ag + k0, lA);
    gload16(Ag + k0 + (size_t)64 * K, lA + 512);
    gload16(Bg + k0, lB);
    gload16(Bg + k0 + (size_t)64 * K, lB + 512);
    __syncthreads();  // drains vmcnt (global_load_lds) + lgkm
    short8 af[4], bfr[4];
#pragma unroll
    for (int i = 0; i < 4; ++i) af[i] = *(const short8*)&lds[aoff + i * 128];
#pragma unroll
    for (int i = 0; i < 4; ++i) bfr[i] = *(const short8*)&lds[boff + i * 128];
#pragma unroll
    for (int mt = 0; mt < 4; ++mt)
#pragma unroll
      for (int nt = 0; nt < 4; ++nt)
        acc[mt][nt] = __builtin_amdgcn_mfma_f32_16x16x32_bf16(af[mt], bfr[nt], acc[mt][nt], 0, 0, 0);
    __syncthreads();
  }
  // epilogue: C/D layout col=lane&15, row=quad*4+reg (m89/m91-verified)
  const int mb = row0 + wm * 64 + quad * 4;
  const int nb = col0 + wn * 64 + l16;
#pragma unroll
  for (int mt = 0; mt < 4; ++mt) {
#pragma unroll
    for (int nt = 0; nt < 4; ++nt) {
      floatx4 a4 = acc[mt][nt];
#pragma unroll
      for (int r = 0; r < 4; ++r) {
        int row = mb + mt * 16 + r;
        int col = nb + nt * 16;
        float val = a4[r];
        if (bias) val += bias[col];
        if (dogelu) val = 0.5f * val * (1.f + erff(val * 0.7071067811865475f));
        size_t idx = (size_t)row * N + col;
        if (resid) val += resid[idx];
        if (outF) outF[idx] = val;
        else outB[idx] = f2bf(val);
      }
    }
  }
}

// ---------------- flash attention, chunked online softmax ----------------
// qkv: [B*T][1536] bf16 (q|k|v, each [h*64+e]). One wave per (b,h,64-query tile);
// lane owns one query row. Keys processed in chunks of 16: one rescale per chunk.
__global__ __launch_bounds__(64) void k_attn(const ushort_t* __restrict__ qkv,
                                             const int* __restrict__ lengths,
                                             ushort_t* __restrict__ o) {
  __shared__ float Ks[64][68];
  __shared__ float Vs[64][68];
  int lane = threadIdx.x;
  int tile = blockIdx.x & 15;
  int bh = blockIdx.x >> 4;
  int b = bh >> 3, h = bh & 7;
  int t = tile * 64 + lane;
  int len = lengths[b];
  size_t qbase = ((size_t)(b * TT + t)) * 1536 + h * HSZ;
  float4 qv[16];
  {
    const ushort_t* qp = qkv + qbase;
#pragma unroll
    for (int i = 0; i < 16; ++i) {
      ushort4 u = *(const ushort4*)(qp + i * 4);
      qv[i] = make_float4(bf2f(u.x), bf2f(u.y), bf2f(u.z), bf2f(u.w));
    }
  }
  float4 acc[16];
#pragma unroll
  for (int i = 0; i < 16; ++i) acc[i] = make_float4(0.f, 0.f, 0.f, 0.f);
  float mrun = -1e30f, lrun = 0.f;
  int nkt = (len + 63) >> 6;
  for (int kt = 0; kt < nkt; ++kt) {
    int s0 = kt * 64;
    __syncthreads();
#pragma unroll
    for (int p = 0; p < 16; ++p) {
      int f = lane + (p << 6);
      int s = f >> 4, e4 = (f & 15) << 2;
      const ushort_t* kp = qkv + ((size_t)(b * TT + s0 + s)) * 1536 + h * HSZ + e4;
      ushort4 ku = *(const ushort4*)(kp + 512);
      ushort4 vu = *(const ushort4*)(kp + 1024);
      *(float4*)&Ks[s][e4] = make_float4(bf2f(ku.x), bf2f(ku.y), bf2f(ku.z), bf2f(ku.w));
      *(float4*)&Vs[s][e4] = make_float4(bf2f(vu.x), bf2f(vu.y), bf2f(vu.z), bf2f(vu.w));
    }
    __syncthreads();
    for (int c4 = 0; c4 < 4; ++c4) {
      float sc[16];
#pragma unroll
      for (int j = 0; j < 16; ++j) {
        const float4* kr = (const float4*)&Ks[c4 * 16 + j][0];
        float s = 0.f;
#pragma unroll
        for (int i = 0; i < 16; ++i) {
          float4 k4 = kr[i];
          s += qv[i].x * k4.x + qv[i].y * k4.y + qv[i].z * k4.z + qv[i].w * k4.w;
        }
        sc[j] = (s0 + c4 * 16 + j < len) ? s * 0.125f : -1e30f;
      }
      float mc = sc[0];
#pragma unroll
      for (int j = 1; j < 16; ++j) mc = fmaxf(mc, sc[j]);
      float mnew = fmaxf(mrun, mc);
      float corr = __expf(mrun - mnew);
      lrun *= corr;
#pragma unroll
      for (int i = 0; i < 16; ++i) {
        acc[i].x *= corr; acc[i].y *= corr; acc[i].z *= corr; acc[i].w *= corr;
      }
#pragma unroll
      for (int j = 0; j < 16; ++j) {
        float p = __expf(sc[j] - mnew);
        lrun += p;
        const float4* vr = (const float4*)&Vs[c4 * 16 + j][0];
#pragma unroll
        for (int i = 0; i < 16; ++i) {
          float4 v4 = vr[i];
          acc[i].x += p * v4.x; acc[i].y += p * v4.y;
          acc[i].z += p * v4.z; acc[i].w += p * v4.w;
        }
      }
      mrun = mnew;
    }
  }
  float inv = (t < len) ? 1.f / lrun : 0.f;  // row mask zeroes padded queries
  ushort_t* op = o + ((size_t)(b * TT + t)) * DD + h * HSZ;
#pragma unroll
  for (int i = 0; i < 16; ++i) {
    ushort4 u;
    u.x = f2bf(acc[i].x * inv); u.y = f2bf(acc[i].y * inv);
    u.z = f2bf(acc[i].z * inv); u.w = f2bf(acc[i].w * inv);
    *(ushort4*)(op + i * 4) = u;
  }
}

// ---------------- attention pooling (per batch), fp32 in ----------------
__global__ __launch_bounds__(256) void k_pool(const float* __restrict__ xn,
                                              const int* __restrict__ lengths,
                                              const float* __restrict__ attn_w,
                                              const float* __restrict__ attn_b,
                                              float* __restrict__ summary) {
  __shared__ __align__(16) float sw[DD];
  __shared__ float sc[TT];
  __shared__ float red[8];
  int tid = threadIdx.x, b = blockIdx.x;
  int len = lengths[b];
  for (int i = tid; i < DD; i += 256) sw[i] = attn_w[i];
  __syncthreads();
  const float* xb = xn + (size_t)b * TT * DD;
  float ab = attn_b[0];
  for (int t = tid; t < TT; t += 256) {
    const float4* xr = (const float4*)(xb + (size_t)t * DD);
    const float4* wr = (const float4*)sw;
    float s = 0.f;
    for (int d = 0; d < DD / 4; ++d) {
      float4 xv = xr[d], wv = wr[d];
      s += xv.x * wv.x + xv.y * wv.y + xv.z * wv.z + xv.w * wv.w;
    }
    sc[t] = s + ab;
  }
  __syncthreads();
  float m = -1e30f;
  for (int t = tid; t < len; t += 256) m = fmaxf(m, sc[t]);
#pragma unroll
  for (int off = 32; off; off >>= 1) m = fmaxf(m, __shfl_down(m, off, 64));
  if ((tid & 63) == 0) red[tid >> 6] = m;
  __syncthreads();
  m = fmaxf(fmaxf(red[0], red[1]), fmaxf(red[2], red[3]));
  float ssum = 0.f;
  for (int t = tid; t < len; t += 256) ssum += __expf(sc[t] - m);
#pragma unroll
  for (int off = 32; off; off >>= 1) ssum += __shfl_down(ssum, off, 64);
  if ((tid & 63) == 0) red[4 + (tid >> 6)] = ssum;
  __syncthreads();
  float inv = 1.f / (red[4] + red[5] + red[6] + red[7]);
  __syncthreads();
  for (int t = tid; t < TT; t += 256) sc[t] = (t < len) ? __expf(sc[t] - m) * inv : 0.f;
  __syncthreads();
  for (int d = tid; d < DD; d += 256) {
    float acc = 0.f;
    for (int t = 0; t < TT; ++t) acc += sc[t] * xb[(size_t)t * DD + d];
    summary[b * DD + d] = acc;
  }
}

// ---------------- classification head ----------------
__global__ __launch_bounds__(64) void k_head(const float* __restrict__ summary,
                                             const float* __restrict__ head_w,
                                             const float* __restrict__ head_b,
                                             float* __restrict__ out) {
  int b = blockIdx.x, j = threadIdx.x;
  if (j < 49) {
    float s = head_b[j];
    for (int d = 0; d < DD; ++d) s += summary[b * DD + d] * head_w[d * 49 + j];
    out[b * 49 + j] = s;
  }
}

extern "C" void kernel_launch(void* const* d_in, const int* in_sizes, int n_in,
                              void* d_out, int out_size, void* d_ws, size_t ws_size,
                              hipStream_t stream) {
  const int* code = (const int*)d_in[0];
  const int* lengths = (const int*)d_in[1];
  const float* emb = (const float*)d_in[2];
  const float* Wq = (const float*)d_in[3];
  const float* Wk = (const float*)d_in[4];
  const float* Wv = (const float*)d_in[5];
  const float* Wo = (const float*)d_in[6];
  const float* bo = (const float*)d_in[7];
  const float* W1 = (const float*)d_in[8];
  const float* b1 = (const float*)d_in[9];
  const float* W2 = (const float*)d_in[10];
  const float* b2 = (const float*)d_in[11];
  const float* ln1_g = (const float*)d_in[12];
  const float* ln1_b = (const float*)d_in[13];
  const float* ln2_g = (const float*)d_in[14];
  const float* ln2_b = (const float*)d_in[15];
  const float* lnf_g = (const float*)d_in[16];
  const float* lnf_b = (const float*)d_in[17];
  const float* attn_w = (const float*)d_in[18];
  const float* attn_b = (const float*)d_in[19];
  const float* head_w = (const float*)d_in[20];
  const float* head_b = (const float*)d_in[21];
  float* out = (float*)d_out;

  const size_t NTOK = (size_t)BB * TT;  // 8192
  // workspace layout (~96.5 MB)
  float* x = (float*)d_ws;                       // 8192*512 fp32
  ushort_t* xn = (ushort_t*)(x + NTOK * DD);     // 8192*512 bf16 (LN out / attn out)
  ushort_t* un = xn + NTOK * DD;                 // union: qkv [8192*1536] | h1 [8192*2048] | xf fp32 [8192*512]
  ushort_t* qkv = un;
  ushort_t* h1 = un;
  float* xf = (float*)un;
  ushort_t* wqt = un + (size_t)NTOK * FF4;       // Wcat^T: 6*1536*512
  ushort_t* wot = wqt + (size_t)LL * 1536 * 512; // 6*512*512
  ushort_t* w1t = wot + (size_t)LL * 512 * 512;  // 6*2048*512
  ushort_t* w2t = w1t + (size_t)LL * 512 * FF4;  // 6*512*2048
  float* summary = (float*)(w2t + (size_t)LL * FF4 * 512);  // 8*512

  // weight prep: fp32 [K][N] -> bf16 [N][K]
  k_transpose<<<dim3(8, 1, 48), 256, 0, stream>>>(Wq, wqt,            64, (long)512 * 64, 8, (long)1536 * 512, (long)64 * 512, 512);
  k_transpose<<<dim3(8, 1, 48), 256, 0, stream>>>(Wk, wqt + 512 * 512, 64, (long)512 * 64, 8, (long)1536 * 512, (long)64 * 512, 512);
  k_transpose<<<dim3(8, 1, 48), 256, 0, stream>>>(Wv, wqt + 1024 * 512, 64, (long)512 * 64, 8, (long)1536 * 512, (long)64 * 512, 512);
  k_transpose<<<dim3(8, 8, 6), 256, 0, stream>>>(Wo, wot, 512, (long)512 * 512, 1, (long)512 * 512, 0, 512);
  k_transpose<<<dim3(8, 32, 6), 256, 0, stream>>>(W1, w1t, 2048, (long)512 * 2048, 1, (long)2048 * 512, 0, 512);
  k_transpose<<<dim3(32, 8, 6), 256, 0, stream>>>(W2, w2t, 512, (long)2048 * 512, 1, (long)512 * 2048, 0, 2048);

  k_embed<<<dim3((unsigned)((NTOK * DD) / 256)), dim3(256), 0, stream>>>(code, emb, x);

  for (int l = 0; l < LL; ++l) {
    k_ln<<<dim3(NTOK / 4), 256, 0, stream>>>(x, xn, nullptr, ln1_g + l * DD, ln1_b + l * DD);
    // fused QKV: M=8192, N=1536, K=512
    k_gemm<<<dim3(12, 64), 256, 0, stream>>>(xn, wqt + (size_t)l * 1536 * 512, nullptr, nullptr,
                                             nullptr, qkv, (int)NTOK, 1536, 512, 0);
    k_attn<<<dim3(BB * HH * (TT / 64)), 64, 0, stream>>>(qkv, lengths, xn);
    // Wo + residual: M=8192, N=512, K=512
    k_gemm<<<dim3(4, 64), 256, 0, stream>>>(xn, wot + (size_t)l * 512 * 512, x, bo + l * DD,
                                            x, nullptr, (int)NTOK, 512, 512, 0);
    k_ln<<<dim3(NTOK / 4), 256, 0, stream>>>(x, xn, nullptr, ln2_g + l * DD, ln2_b + l * DD);
    // W1 + bias + GELU -> h1 (bf16): M=8192, N=2048, K=512
    k_gemm<<<dim3(16, 64), 256, 0, stream>>>(xn, w1t + (size_t)l * 512 * FF4, nullptr, b1 + l * FF4,
                                             nullptr, h1, (int)NTOK, FF4, 512, 1);
    // W2 + bias + residual: M=8192, N=512, K=2048
    k_gemm<<<dim3(4, 64), 256, 0, stream>>>(h1, w2t + (size_t)l * FF4 * 512, x, b2 + l * DD,
                                            x, nullptr, (int)NTOK, 512, FF4, 0);
  }
  k_ln<<<dim3(NTOK / 4), 256, 0, stream>>>(x, nullptr, xf, lnf_g, lnf_b);
  k_pool<<<dim3(BB), 256, 0, stream>>>(xf, lengths, attn_w, attn_b, summary);
  k_head<<<dim3(BB), 64, 0, stream>>>(summary, head_w, head_b, out);
}

// Round 3
// 2151.755 us; speedup vs baseline: 4.9199x; 3.0604x over previous
//
#include <hip/hip_runtime.h>
#include <math.h>

#define TT 1024
#define BB 8
#define DD 512
#define HH 8
#define HSZ 64
#define LL 6
#define FF4 2048

typedef __attribute__((ext_vector_type(8))) short short8;
typedef __attribute__((ext_vector_type(4))) float floatx4;
typedef unsigned short ushort_t;
typedef unsigned int uint_t;

__device__ __forceinline__ ushort_t f2bf(float f) {
  uint_t u = __float_as_uint(f);
  u += 0x7fff + ((u >> 16) & 1);  // RNE
  return (ushort_t)(u >> 16);
}
__device__ __forceinline__ float bf2f(ushort_t h) {
  return __uint_as_float(((uint_t)h) << 16);
}

__device__ __forceinline__ void gload16(const void* g, void* l) {
  __builtin_amdgcn_global_load_lds((const __attribute__((address_space(1))) void*)g,
                                   (__attribute__((address_space(3))) void*)l, 16, 0, 0);
}

// ---------------- embed + positional encoding ----------------
__global__ __launch_bounds__(256) void k_embed(const int* __restrict__ code,
                                               const float* __restrict__ emb,
                                               float* __restrict__ x) {
  int idx = blockIdx.x * 256 + threadIdx.x;  // over B*T*D
  int c = idx & (DD - 1);
  int bt = idx >> 9;
  int t = bt & (TT - 1);
  int f = c >> 4, e = c & 15;
  int vv = code[bt * 32 + f];
  int i = c >> 1;
  float freq = expf((float)(2 * i) * (-9.210340371976184f / 512.f));
  float ang = (float)t * freq;
  float pe = (c & 1) ? cosf(ang) : sinf(ang);
  x[idx] = emb[vv * 16 + e] + pe;
}

// ---------------- layernorm: one wave per 512-wide row, fp32 in, bf16 (or fp32) out ----------------
__global__ __launch_bounds__(256) void k_ln(const float* __restrict__ x,
                                            ushort_t* __restrict__ yB,
                                            float* __restrict__ yF,
                                            const float* __restrict__ g,
                                            const float* __restrict__ b) {
  int wave = threadIdx.x >> 6, lane = threadIdx.x & 63;
  int row = blockIdx.x * 4 + wave;
  const float* xr = x + (size_t)row * DD;
  float v[8];
  float s = 0.f;
#pragma unroll
  for (int j = 0; j < 8; ++j) { v[j] = xr[lane + 64 * j]; s += v[j]; }
#pragma unroll
  for (int off = 32; off; off >>= 1) s += __shfl_down(s, off, 64);
  float mean = __shfl(s, 0, 64) * (1.f / DD);
  float qv = 0.f;
#pragma unroll
  for (int j = 0; j < 8; ++j) { float d = v[j] - mean; qv += d * d; }
#pragma unroll
  for (int off = 32; off; off >>= 1) qv += __shfl_down(qv, off, 64);
  float rs = rsqrtf(__shfl(qv, 0, 64) * (1.f / DD) + 1e-5f);
#pragma unroll
  for (int j = 0; j < 8; ++j) {
    int c = lane + 64 * j;
    float val = (v[j] - mean) * rs * g[c] + b[c];
    if (yB) yB[(size_t)row * DD + c] = f2bf(val);
    else    yF[(size_t)row * DD + c] = val;
  }
}

// ---------------- fp32 -> bf16 transposed weight prep ----------------
__global__ __launch_bounds__(256) void k_transpose(const float* __restrict__ in,
                                                   ushort_t* __restrict__ out,
                                                   int Nin, long in_ms, int nh,
                                                   long os_l, long os_h, int out_ld) {
  __shared__ float t4[64][65];
  int mz = blockIdx.z;
  const float* ip = in + (size_t)mz * in_ms;
  ushort_t* op = out + (size_t)(mz / nh) * os_l + (size_t)(mz % nh) * os_h;
  int k0 = blockIdx.x * 64, n0 = blockIdx.y * 64;
  int c = threadIdx.x & 63, r0 = threadIdx.x >> 6;
#pragma unroll
  for (int i = 0; i < 16; ++i) {
    int r = r0 * 16 + i;
    t4[r][c] = ip[(size_t)(k0 + r) * Nin + n0 + c];
  }
  __syncthreads();
#pragma unroll
  for (int i = 0; i < 16; ++i) {
    int n = r0 * 16 + i;
    op[(size_t)(n0 + n) * out_ld + k0 + c] = f2bf(t4[c][n]);
  }
}

// ---------------- bf16 MFMA GEMM (m97 structure) ----------------
__global__ __launch_bounds__(256) void k_gemm(const ushort_t* __restrict__ A,
                                              const ushort_t* __restrict__ Bt,
                                              const float* __restrict__ resid,
                                              const float* __restrict__ bias,
                                              float* __restrict__ outF,
                                              ushort_t* __restrict__ outB,
                                              int M, int N, int K, int dogelu) {
  __shared__ short lds[8192];
  const int tid = threadIdx.x;
  const int w = tid >> 6, lane = tid & 63;
  const int quad = lane >> 4, l16 = lane & 15;
  const int wm = w >> 1, wn = w & 1;
  const int row0 = blockIdx.y * 128, col0 = blockIdx.x * 128;
  const short* Ag = (const short*)A + (size_t)(row0 + lane) * K + w * 8;
  const short* Bg = (const short*)Bt + (size_t)(col0 + lane) * K + w * 8;
  short* lA = &lds[w * 1024];
  short* lB = &lds[4096 + w * 1024];
  floatx4 acc[4][4] = {};
  const int aoff = (quad * 128 + wm * 64 + l16) * 8;
  const int boff = 4096 + (quad * 128 + wn * 64 + l16) * 8;
  for (int k0 = 0; k0 < K; k0 += 32) {
    gload16(Ag + k0, lA);
    gload16(Ag + k0 + (size_t)64 * K, lA + 512);
    gload16(Bg + k0, lB);
    gload16(Bg + k0 + (size_t)64 * K, lB + 512);
    __syncthreads();
    short8 af[4], bfr[4];
#pragma unroll
    for (int i = 0; i < 4; ++i) af[i] = *(const short8*)&lds[aoff + i * 128];
#pragma unroll
    for (int i = 0; i < 4; ++i) bfr[i] = *(const short8*)&lds[boff + i * 128];
#pragma unroll
    for (int mt = 0; mt < 4; ++mt)
#pragma unroll
      for (int nt = 0; nt < 4; ++nt)
        acc[mt][nt] = __builtin_amdgcn_mfma_f32_16x16x32_bf16(af[mt], bfr[nt], acc[mt][nt], 0, 0, 0);
    __syncthreads();
  }
  const int mb = row0 + wm * 64 + quad * 4;
  const int nb = col0 + wn * 64 + l16;
#pragma unroll
  for (int mt = 0; mt < 4; ++mt) {
#pragma unroll
    for (int nt = 0; nt < 4; ++nt) {
      floatx4 a4 = acc[mt][nt];
#pragma unroll
      for (int r = 0; r < 4; ++r) {
        int row = mb + mt * 16 + r;
        int col = nb + nt * 16;
        float val = a4[r];
        if (bias) val += bias[col];
        if (dogelu) val = 0.5f * val * (1.f + erff(val * 0.7071067811865475f));
        size_t idx = (size_t)row * N + col;
        if (resid) val += resid[idx];
        if (outF) outF[idx] = val;
        else outB[idx] = f2bf(val);
      }
    }
  }
}

// ---------------- MFMA flash attention ----------------
// qkv: [B*T][1536] bf16 (q|k|v). Block = (b, h, 64-query tile), 4 waves x 16 queries.
// K-tile = 64 keys: Ks[key][dim], Vt[dim][key] staged bf16 (pad 72 -> 2-way only).
// QK^T: 8 MFMAs/wave; online softmax in C-layout regs; P via per-wave LDS to
// A-layout (m120 pattern); PV: 8 MFMAs/wave.
__global__ __launch_bounds__(256) void k_attn(const ushort_t* __restrict__ qkv,
                                              const int* __restrict__ lengths,
                                              ushort_t* __restrict__ o) {
  __shared__ ushort_t Ks[64 * 72];
  __shared__ ushort_t Vt[64 * 72];
  __shared__ ushort_t Ps[4][16 * 72];
  const int tid = threadIdx.x;
  const int w = tid >> 6, lane = tid & 63;
  const int quad = lane >> 4, l16 = lane & 15;
  const int tile = blockIdx.x & 15;
  const int bh = blockIdx.x >> 4;
  const int b = bh >> 3, h = bh & 7;
  const int len = lengths[b];
  // Q A-fragment: A[m=l16][k=quad*8+j], two k-chunks of 32
  const int tqa = tile * 64 + w * 16 + l16;
  const ushort_t* qp = qkv + ((size_t)(b * TT + tqa)) * 1536 + h * HSZ + quad * 8;
  short8 qf0 = *(const short8*)qp;
  short8 qf1 = *(const short8*)(qp + 32);
  floatx4 oacc[4] = {};
  float mrun[4], lrun[4];
#pragma unroll
  for (int r = 0; r < 4; ++r) { mrun[r] = -1e30f; lrun[r] = 0.f; }
  const int skey = tid >> 2, sseg = (tid & 3) << 4;        // K staging
  const int vkp = (tid & 31) << 1, vds = (tid >> 5) << 3;  // V staging (2 keys x 8 dims)
  const int nkt = (len + 63) >> 6;
  for (int kt = 0; kt < nkt; ++kt) {
    const int s0 = kt * 64;
    __syncthreads();
    {
      const ushort_t* kp = qkv + ((size_t)(b * TT + s0 + skey)) * 1536 + 512 + h * HSZ + sseg;
      short8 k0 = *(const short8*)kp;
      short8 k1 = *(const short8*)(kp + 8);
      *(short8*)&Ks[skey * 72 + sseg] = k0;
      *(short8*)&Ks[skey * 72 + sseg + 8] = k1;
      const ushort_t* vp0 = qkv + ((size_t)(b * TT + s0 + vkp)) * 1536 + 1024 + h * HSZ + vds;
      short8 v0 = *(const short8*)vp0;
      short8 v1 = *(const short8*)(vp0 + 1536);
#pragma unroll
      for (int i = 0; i < 8; ++i) {
        ushort2 pr;
        pr.x = (ushort_t)v0[i];
        pr.y = (ushort_t)v1[i];
        *(ushort2*)&Vt[(vds + i) * 72 + vkp] = pr;
      }
    }
    __syncthreads();
    // QK^T
    floatx4 sacc[4] = {};
#pragma unroll
    for (int nt = 0; nt < 4; ++nt) {
      short8 kf0 = *(const short8*)&Ks[(nt * 16 + l16) * 72 + quad * 8];
      short8 kf1 = *(const short8*)&Ks[(nt * 16 + l16) * 72 + 32 + quad * 8];
      sacc[nt] = __builtin_amdgcn_mfma_f32_16x16x32_bf16(qf0, kf0, sacc[nt], 0, 0, 0);
      sacc[nt] = __builtin_amdgcn_mfma_f32_16x16x32_bf16(qf1, kf1, sacc[nt], 0, 0, 0);
    }
    // online softmax; C layout: col = nt*16+l16 (key), row = quad*4+r (query)
    float p[4][4], mx[4];
#pragma unroll
    for (int r = 0; r < 4; ++r) {
      float m = -1e30f;
#pragma unroll
      for (int nt = 0; nt < 4; ++nt) {
        float s = (s0 + nt * 16 + l16 < len) ? sacc[nt][r] * 0.125f : -1e30f;
        p[nt][r] = s;
        m = fmaxf(m, s);
      }
      mx[r] = m;
    }
#pragma unroll
    for (int off = 1; off < 16; off <<= 1) {
#pragma unroll
      for (int r = 0; r < 4; ++r) mx[r] = fmaxf(mx[r], __shfl_xor(mx[r], off, 64));
    }
    float corr[4], rs[4];
#pragma unroll
    for (int r = 0; r < 4; ++r) {
      float mnew = fmaxf(mrun[r], mx[r]);
      corr[r] = __expf(mrun[r] - mnew);
      mrun[r] = mnew;
      float s = 0.f;
#pragma unroll
      for (int nt = 0; nt < 4; ++nt) {
        float e = __expf(p[nt][r] - mnew);
        p[nt][r] = e;
        s += e;
      }
      rs[r] = s;
    }
#pragma unroll
    for (int off = 1; off < 16; off <<= 1) {
#pragma unroll
      for (int r = 0; r < 4; ++r) rs[r] += __shfl_xor(rs[r], off, 64);
    }
#pragma unroll
    for (int r = 0; r < 4; ++r) {
      lrun[r] = lrun[r] * corr[r] + rs[r];
#pragma unroll
      for (int nt = 0; nt < 4; ++nt) {
        oacc[nt][r] *= corr[r];
        Ps[w][(quad * 4 + r) * 72 + nt * 16 + l16] = f2bf(p[nt][r]);
      }
    }
    // PV (P per-wave: no barrier needed; Vt protected by top-of-loop barrier)
    short8 pf0 = *(const short8*)&Ps[w][l16 * 72 + quad * 8];
    short8 pf1 = *(const short8*)&Ps[w][l16 * 72 + 32 + quad * 8];
#pragma unroll
    for (int nt = 0; nt < 4; ++nt) {
      short8 vf0 = *(const short8*)&Vt[(nt * 16 + l16) * 72 + quad * 8];
      short8 vf1 = *(const short8*)&Vt[(nt * 16 + l16) * 72 + 32 + quad * 8];
      oacc[nt] = __builtin_amdgcn_mfma_f32_16x16x32_bf16(pf0, vf0, oacc[nt], 0, 0, 0);
      oacc[nt] = __builtin_amdgcn_mfma_f32_16x16x32_bf16(pf1, vf1, oacc[nt], 0, 0, 0);
    }
  }
#pragma unroll
  for (int r = 0; r < 4; ++r) {
    int t = tile * 64 + w * 16 + quad * 4 + r;
    float inv = (t < len) ? 1.f / lrun[r] : 0.f;  // row mask
    ushort_t* op = o + ((size_t)(b * TT + t)) * DD + h * HSZ + l16;
#pragma unroll
    for (int nt = 0; nt < 4; ++nt) op[nt * 16] = f2bf(oacc[nt][r] * inv);
  }
}

// ---------------- attention pooling (per batch), fp32 in ----------------
__global__ __launch_bounds__(256) void k_pool(const float* __restrict__ xn,
                                              const int* __restrict__ lengths,
                                              const float* __restrict__ attn_w,
                                              const float* __restrict__ attn_b,
                                              float* __restrict__ summary) {
  __shared__ __align__(16) float sw[DD];
  __shared__ float sc[TT];
  __shared__ float red[8];
  int tid = threadIdx.x, b = blockIdx.x;
  int len = lengths[b];
  for (int i = tid; i < DD; i += 256) sw[i] = attn_w[i];
  __syncthreads();
  const float* xb = xn + (size_t)b * TT * DD;
  float ab = attn_b[0];
  for (int t = tid; t < TT; t += 256) {
    const float4* xr = (const float4*)(xb + (size_t)t * DD);
    const float4* wr = (const float4*)sw;
    float s = 0.f;
    for (int d = 0; d < DD / 4; ++d) {
      float4 xv = xr[d], wv = wr[d];
      s += xv.x * wv.x + xv.y * wv.y + xv.z * wv.z + xv.w * wv.w;
    }
    sc[t] = s + ab;
  }
  __syncthreads();
  float m = -1e30f;
  for (int t = tid; t < len; t += 256) m = fmaxf(m, sc[t]);
#pragma unroll
  for (int off = 32; off; off >>= 1) m = fmaxf(m, __shfl_down(m, off, 64));
  if ((tid & 63) == 0) red[tid >> 6] = m;
  __syncthreads();
  m = fmaxf(fmaxf(red[0], red[1]), fmaxf(red[2], red[3]));
  float ssum = 0.f;
  for (int t = tid; t < len; t += 256) ssum += __expf(sc[t] - m);
#pragma unroll
  for (int off = 32; off; off >>= 1) ssum += __shfl_down(ssum, off, 64);
  if ((tid & 63) == 0) red[4 + (tid >> 6)] = ssum;
  __syncthreads();
  float inv = 1.f / (red[4] + red[5] + red[6] + red[7]);
  __syncthreads();
  for (int t = tid; t < TT; t += 256) sc[t] = (t < len) ? __expf(sc[t] - m) * inv : 0.f;
  __syncthreads();
  for (int d = tid; d < DD; d += 256) {
    float acc = 0.f;
    for (int t = 0; t < TT; ++t) acc += sc[t] * xb[(size_t)t * DD + d];
    summary[b * DD + d] = acc;
  }
}

// ---------------- classification head ----------------
__global__ __launch_bounds__(64) void k_head(const float* __restrict__ summary,
                                             const float* __restrict__ head_w,
                                             const float* __restrict__ head_b,
                                             float* __restrict__ out) {
  int b = blockIdx.x, j = threadIdx.x;
  if (j < 49) {
    float s = head_b[j];
    for (int d = 0; d < DD; ++d) s += summary[b * DD + d] * head_w[d * 49 + j];
    out[b * 49 + j] = s;
  }
}

extern "C" void kernel_launch(void* const* d_in, const int* in_sizes, int n_in,
                              void* d_out, int out_size, void* d_ws, size_t ws_size,
                              hipStream_t stream) {
  const int* code = (const int*)d_in[0];
  const int* lengths = (const int*)d_in[1];
  const float* emb = (const float*)d_in[2];
  const float* Wq = (const float*)d_in[3];
  const float* Wk = (const float*)d_in[4];
  const float* Wv = (const float*)d_in[5];
  const float* Wo = (const float*)d_in[6];
  const float* bo = (const float*)d_in[7];
  const float* W1 = (const float*)d_in[8];
  const float* b1 = (const float*)d_in[9];
  const float* W2 = (const float*)d_in[10];
  const float* b2 = (const float*)d_in[11];
  const float* ln1_g = (const float*)d_in[12];
  const float* ln1_b = (const float*)d_in[13];
  const float* ln2_g = (const float*)d_in[14];
  const float* ln2_b = (const float*)d_in[15];
  const float* lnf_g = (const float*)d_in[16];
  const float* lnf_b = (const float*)d_in[17];
  const float* attn_w = (const float*)d_in[18];
  const float* attn_b = (const float*)d_in[19];
  const float* head_w = (const float*)d_in[20];
  const float* head_b = (const float*)d_in[21];
  float* out = (float*)d_out;

  const size_t NTOK = (size_t)BB * TT;  // 8192
  float* x = (float*)d_ws;                       // 8192*512 fp32
  ushort_t* xn = (ushort_t*)(x + NTOK * DD);     // 8192*512 bf16
  ushort_t* un = xn + NTOK * DD;                 // union: qkv | h1 | xf
  ushort_t* qkv = un;
  ushort_t* h1 = un;
  float* xf = (float*)un;
  ushort_t* wqt = un + (size_t)NTOK * FF4;
  ushort_t* wot = wqt + (size_t)LL * 1536 * 512;
  ushort_t* w1t = wot + (size_t)LL * 512 * 512;
  ushort_t* w2t = w1t + (size_t)LL * 512 * FF4;
  float* summary = (float*)(w2t + (size_t)LL * FF4 * 512);

  k_transpose<<<dim3(8, 1, 48), 256, 0, stream>>>(Wq, wqt,             64, (long)512 * 64, 8, (long)1536 * 512, (long)64 * 512, 512);
  k_transpose<<<dim3(8, 1, 48), 256, 0, stream>>>(Wk, wqt + 512 * 512,  64, (long)512 * 64, 8, (long)1536 * 512, (long)64 * 512, 512);
  k_transpose<<<dim3(8, 1, 48), 256, 0, stream>>>(Wv, wqt + 1024 * 512, 64, (long)512 * 64, 8, (long)1536 * 512, (long)64 * 512, 512);
  k_transpose<<<dim3(8, 8, 6), 256, 0, stream>>>(Wo, wot, 512, (long)512 * 512, 1, (long)512 * 512, 0, 512);
  k_transpose<<<dim3(8, 32, 6), 256, 0, stream>>>(W1, w1t, 2048, (long)512 * 2048, 1, (long)2048 * 512, 0, 512);
  k_transpose<<<dim3(32, 8, 6), 256, 0, stream>>>(W2, w2t, 512, (long)2048 * 512, 1, (long)512 * 2048, 0, 2048);

  k_embed<<<dim3((unsigned)((NTOK * DD) / 256)), dim3(256), 0, stream>>>(code, emb, x);

  for (int l = 0; l < LL; ++l) {
    k_ln<<<dim3(NTOK / 4), 256, 0, stream>>>(x, xn, nullptr, ln1_g + l * DD, ln1_b + l * DD);
    k_gemm<<<dim3(12, 64), 256, 0, stream>>>(xn, wqt + (size_t)l * 1536 * 512, nullptr, nullptr,
                                             nullptr, qkv, (int)NTOK, 1536, 512, 0);
    k_attn<<<dim3(BB * HH * (TT / 64)), 256, 0, stream>>>(qkv, lengths, xn);
    k_gemm<<<dim3(4, 64), 256, 0, stream>>>(xn, wot + (size_t)l * 512 * 512, x, bo + l * DD,
                                            x, nullptr, (int)NTOK, 512, 512, 0);
    k_ln<<<dim3(NTOK / 4), 256, 0, stream>>>(x, xn, nullptr, ln2_g + l * DD, ln2_b + l * DD);
    k_gemm<<<dim3(16, 64), 256, 0, stream>>>(xn, w1t + (size_t)l * 512 * FF4, nullptr, b1 + l * FF4,
                                             nullptr, h1, (int)NTOK, FF4, 512, 1);
    k_gemm<<<dim3(4, 64), 256, 0, stream>>>(h1, w2t + (size_t)l * FF4 * 512, x, b2 + l * DD,
                                            x, nullptr, (int)NTOK, 512, FF4, 0);
  }
  k_ln<<<dim3(NTOK / 4), 256, 0, stream>>>(x, nullptr, xf, lnf_g, lnf_b);
  k_pool<<<dim3(BB), 256, 0, stream>>>(xf, lengths, attn_w, attn_b, summary);
  k_head<<<dim3(BB), 64, 0, stream>>>(summary, head_w, head_b, out);
}

// Round 4
// 1930.345 us; speedup vs baseline: 5.4842x; 1.1147x over previous
//
#include <hip/hip_runtime.h>
#include <math.h>

#define TT 1024
#define BB 8
#define DD 512
#define HH 8
#define HSZ 64
#define LL 6
#define FF4 2048

typedef __attribute__((ext_vector_type(8))) short short8;
typedef __attribute__((ext_vector_type(4))) float floatx4;
typedef unsigned short ushort_t;
typedef unsigned int uint_t;

__device__ __forceinline__ ushort_t f2bf(float f) {
  uint_t u = __float_as_uint(f);
  u += 0x7fff + ((u >> 16) & 1);  // RNE
  return (ushort_t)(u >> 16);
}
__device__ __forceinline__ float bf2f(ushort_t h) {
  return __uint_as_float(((uint_t)h) << 16);
}

__device__ __forceinline__ void gload16(const void* g, void* l) {
  __builtin_amdgcn_global_load_lds((const __attribute__((address_space(1))) void*)g,
                                   (__attribute__((address_space(3))) void*)l, 16, 0, 0);
}

// ---------------- embed + positional encoding ----------------
__global__ __launch_bounds__(256) void k_embed(const int* __restrict__ code,
                                               const float* __restrict__ emb,
                                               float* __restrict__ x) {
  int idx = blockIdx.x * 256 + threadIdx.x;  // over B*T*D
  int c = idx & (DD - 1);
  int bt = idx >> 9;
  int t = bt & (TT - 1);
  int f = c >> 4, e = c & 15;
  int vv = code[bt * 32 + f];
  int i = c >> 1;
  float freq = expf((float)(2 * i) * (-9.210340371976184f / 512.f));
  float ang = (float)t * freq;
  float pe = (c & 1) ? cosf(ang) : sinf(ang);
  x[idx] = emb[vv * 16 + e] + pe;
}

// ---------------- layernorm: one wave per 512-wide row, fp32 in, bf16 (or fp32) out ----------------
__global__ __launch_bounds__(256) void k_ln(const float* __restrict__ x,
                                            ushort_t* __restrict__ yB,
                                            float* __restrict__ yF,
                                            const float* __restrict__ g,
                                            const float* __restrict__ b) {
  int wave = threadIdx.x >> 6, lane = threadIdx.x & 63;
  int row = blockIdx.x * 4 + wave;
  const float* xr = x + (size_t)row * DD;
  float v[8];
  float s = 0.f;
#pragma unroll
  for (int j = 0; j < 8; ++j) { v[j] = xr[lane + 64 * j]; s += v[j]; }
#pragma unroll
  for (int off = 32; off; off >>= 1) s += __shfl_down(s, off, 64);
  float mean = __shfl(s, 0, 64) * (1.f / DD);
  float qv = 0.f;
#pragma unroll
  for (int j = 0; j < 8; ++j) { float d = v[j] - mean; qv += d * d; }
#pragma unroll
  for (int off = 32; off; off >>= 1) qv += __shfl_down(qv, off, 64);
  float rs = rsqrtf(__shfl(qv, 0, 64) * (1.f / DD) + 1e-5f);
#pragma unroll
  for (int j = 0; j < 8; ++j) {
    int c = lane + 64 * j;
    float val = (v[j] - mean) * rs * g[c] + b[c];
    if (yB) yB[(size_t)row * DD + c] = f2bf(val);
    else    yF[(size_t)row * DD + c] = val;
  }
}

// ---------------- fp32 -> bf16 transposed weight prep ----------------
__global__ __launch_bounds__(256) void k_transpose(const float* __restrict__ in,
                                                   ushort_t* __restrict__ out,
                                                   int Nin, long in_ms, int nh,
                                                   long os_l, long os_h, int out_ld) {
  __shared__ float t4[64][65];
  int mz = blockIdx.z;
  const float* ip = in + (size_t)mz * in_ms;
  ushort_t* op = out + (size_t)(mz / nh) * os_l + (size_t)(mz % nh) * os_h;
  int k0 = blockIdx.x * 64, n0 = blockIdx.y * 64;
  int c = threadIdx.x & 63, r0 = threadIdx.x >> 6;
#pragma unroll
  for (int i = 0; i < 16; ++i) {
    int r = r0 * 16 + i;
    t4[r][c] = ip[(size_t)(k0 + r) * Nin + n0 + c];
  }
  __syncthreads();
#pragma unroll
  for (int i = 0; i < 16; ++i) {
    int n = r0 * 16 + i;
    op[(size_t)(n0 + n) * out_ld + k0 + c] = f2bf(t4[c][n]);
  }
}

// ---------------- bf16 MFMA GEMM, 128x128 tile (m97 structure) ----------------
__global__ __launch_bounds__(256) void k_gemm(const ushort_t* __restrict__ A,
                                              const ushort_t* __restrict__ Bt,
                                              const float* __restrict__ resid,
                                              const float* __restrict__ bias,
                                              float* __restrict__ outF,
                                              ushort_t* __restrict__ outB,
                                              int M, int N, int K, int dogelu) {
  __shared__ short lds[8192];
  const int tid = threadIdx.x;
  const int w = tid >> 6, lane = tid & 63;
  const int quad = lane >> 4, l16 = lane & 15;
  const int wm = w >> 1, wn = w & 1;
  const int row0 = blockIdx.y * 128, col0 = blockIdx.x * 128;
  const short* Ag = (const short*)A + (size_t)(row0 + lane) * K + w * 8;
  const short* Bg = (const short*)Bt + (size_t)(col0 + lane) * K + w * 8;
  short* lA = &lds[w * 1024];
  short* lB = &lds[4096 + w * 1024];
  floatx4 acc[4][4] = {};
  const int aoff = (quad * 128 + wm * 64 + l16) * 8;
  const int boff = 4096 + (quad * 128 + wn * 64 + l16) * 8;
  for (int k0 = 0; k0 < K; k0 += 32) {
    gload16(Ag + k0, lA);
    gload16(Ag + k0 + (size_t)64 * K, lA + 512);
    gload16(Bg + k0, lB);
    gload16(Bg + k0 + (size_t)64 * K, lB + 512);
    __syncthreads();
    short8 af[4], bfr[4];
#pragma unroll
    for (int i = 0; i < 4; ++i) af[i] = *(const short8*)&lds[aoff + i * 128];
#pragma unroll
    for (int i = 0; i < 4; ++i) bfr[i] = *(const short8*)&lds[boff + i * 128];
#pragma unroll
    for (int mt = 0; mt < 4; ++mt)
#pragma unroll
      for (int nt = 0; nt < 4; ++nt)
        acc[mt][nt] = __builtin_amdgcn_mfma_f32_16x16x32_bf16(af[mt], bfr[nt], acc[mt][nt], 0, 0, 0);
    __syncthreads();
  }
  const int mb = row0 + wm * 64 + quad * 4;
  const int nb = col0 + wn * 64 + l16;
#pragma unroll
  for (int mt = 0; mt < 4; ++mt) {
#pragma unroll
    for (int nt = 0; nt < 4; ++nt) {
      floatx4 a4 = acc[mt][nt];
#pragma unroll
      for (int r = 0; r < 4; ++r) {
        int row = mb + mt * 16 + r;
        int col = nb + nt * 16;
        float val = a4[r];
        if (bias) val += bias[col];
        if (dogelu) val = 0.5f * val * (1.f + erff(val * 0.7071067811865475f));
        size_t idx = (size_t)row * N + col;
        if (resid) val += resid[idx];
        if (outF) outF[idx] = val;
        else outB[idx] = f2bf(val);
      }
    }
  }
}

// ---------------- bf16 MFMA GEMM, 64x128 tile (for N=512: 2 blocks/CU) ----------------
// Grid must be (4, M/64). XCD swizzle: ids {c, c+8, c+16, c+24} share a row-block
// so the 4 column blocks of one row land on one XCD (A fetched once per XCD L2).
__global__ __launch_bounds__(256) void k_gemm64(const ushort_t* __restrict__ A,
                                                const ushort_t* __restrict__ Bt,
                                                const float* __restrict__ resid,
                                                const float* __restrict__ bias,
                                                float* __restrict__ outF,
                                                ushort_t* __restrict__ outB,
                                                int M, int N, int K, int dogelu) {
  __shared__ short lds[6144];  // A 64x32 (2KB->1024 sh... 64*32=2048 sh) + B 128x32 (4096 sh)
  const int tid = threadIdx.x;
  const int w = tid >> 6, lane = tid & 63;
  const int quad = lane >> 4, l16 = lane & 15;
  const int wm = w >> 1, wn = w & 1;
  int bx, by;
  if (gridDim.x == 4 && (gridDim.y & 7) == 0) {
    int id = blockIdx.y * 4 + blockIdx.x;
    bx = (id >> 3) & 3;
    by = ((id >> 5) << 3) | (id & 7);
  } else {
    bx = blockIdx.x; by = blockIdx.y;
  }
  const int row0 = by * 64, col0 = bx * 128;
  const short* Ag = (const short*)A + (size_t)(row0 + lane) * K + w * 8;
  const short* Bg = (const short*)Bt + (size_t)(col0 + lane) * K + w * 8;
  short* lA = &lds[w * 512];          // seg w: 64 rows x 8 shorts
  short* lB = &lds[2048 + w * 1024];  // seg w: 128 cols x 8 shorts
  floatx4 acc[2][4] = {};
  const int aoff = quad * 512 + (wm * 32 + l16) * 8;
  const int boff = 2048 + quad * 1024 + (wn * 64 + l16) * 8;
  for (int k0 = 0; k0 < K; k0 += 32) {
    gload16(Ag + k0, lA);
    gload16(Bg + k0, lB);
    gload16(Bg + k0 + (size_t)64 * K, lB + 512);
    __syncthreads();
    short8 af[2], bfr[4];
#pragma unroll
    for (int i = 0; i < 2; ++i) af[i] = *(const short8*)&lds[aoff + i * 128];
#pragma unroll
    for (int i = 0; i < 4; ++i) bfr[i] = *(const short8*)&lds[boff + i * 128];
#pragma unroll
    for (int mt = 0; mt < 2; ++mt)
#pragma unroll
      for (int nt = 0; nt < 4; ++nt)
        acc[mt][nt] = __builtin_amdgcn_mfma_f32_16x16x32_bf16(af[mt], bfr[nt], acc[mt][nt], 0, 0, 0);
    __syncthreads();
  }
  const int mb = row0 + wm * 32 + quad * 4;
  const int nb = col0 + wn * 64 + l16;
#pragma unroll
  for (int mt = 0; mt < 2; ++mt) {
#pragma unroll
    for (int nt = 0; nt < 4; ++nt) {
      floatx4 a4 = acc[mt][nt];
#pragma unroll
      for (int r = 0; r < 4; ++r) {
        int row = mb + mt * 16 + r;
        int col = nb + nt * 16;
        float val = a4[r];
        if (bias) val += bias[col];
        if (dogelu) val = 0.5f * val * (1.f + erff(val * 0.7071067811865475f));
        size_t idx = (size_t)row * N + col;
        if (resid) val += resid[idx];
        if (outF) outF[idx] = val;
        else outB[idx] = f2bf(val);
      }
    }
  }
}

// ---------------- MFMA flash attention ----------------
__global__ __launch_bounds__(256) void k_attn(const ushort_t* __restrict__ qkv,
                                              const int* __restrict__ lengths,
                                              ushort_t* __restrict__ o) {
  __shared__ ushort_t Ks[64 * 72];
  __shared__ ushort_t Vt[64 * 72];
  __shared__ ushort_t Ps[4][16 * 72];
  const int tid = threadIdx.x;
  const int w = tid >> 6, lane = tid & 63;
  const int quad = lane >> 4, l16 = lane & 15;
  const int tile = blockIdx.x & 15;
  const int bh = blockIdx.x >> 4;
  const int b = bh >> 3, h = bh & 7;
  const int len = lengths[b];
  const int tqa = tile * 64 + w * 16 + l16;
  const ushort_t* qp = qkv + ((size_t)(b * TT + tqa)) * 1536 + h * HSZ + quad * 8;
  short8 qf0 = *(const short8*)qp;
  short8 qf1 = *(const short8*)(qp + 32);
  floatx4 oacc[4] = {};
  float mrun[4], lrun[4];
#pragma unroll
  for (int r = 0; r < 4; ++r) { mrun[r] = -1e30f; lrun[r] = 0.f; }
  const int skey = tid >> 2, sseg = (tid & 3) << 4;
  const int vkp = (tid & 31) << 1, vds = (tid >> 5) << 3;
  const int nkt = (len + 63) >> 6;
  for (int kt = 0; kt < nkt; ++kt) {
    const int s0 = kt * 64;
    __syncthreads();
    {
      const ushort_t* kp = qkv + ((size_t)(b * TT + s0 + skey)) * 1536 + 512 + h * HSZ + sseg;
      short8 k0 = *(const short8*)kp;
      short8 k1 = *(const short8*)(kp + 8);
      *(short8*)&Ks[skey * 72 + sseg] = k0;
      *(short8*)&Ks[skey * 72 + sseg + 8] = k1;
      const ushort_t* vp0 = qkv + ((size_t)(b * TT + s0 + vkp)) * 1536 + 1024 + h * HSZ + vds;
      short8 v0 = *(const short8*)vp0;
      short8 v1 = *(const short8*)(vp0 + 1536);
#pragma unroll
      for (int i = 0; i < 8; ++i) {
        ushort2 pr;
        pr.x = (ushort_t)v0[i];
        pr.y = (ushort_t)v1[i];
        *(ushort2*)&Vt[(vds + i) * 72 + vkp] = pr;
      }
    }
    __syncthreads();
    floatx4 sacc[4] = {};
#pragma unroll
    for (int nt = 0; nt < 4; ++nt) {
      short8 kf0 = *(const short8*)&Ks[(nt * 16 + l16) * 72 + quad * 8];
      short8 kf1 = *(const short8*)&Ks[(nt * 16 + l16) * 72 + 32 + quad * 8];
      sacc[nt] = __builtin_amdgcn_mfma_f32_16x16x32_bf16(qf0, kf0, sacc[nt], 0, 0, 0);
      sacc[nt] = __builtin_amdgcn_mfma_f32_16x16x32_bf16(qf1, kf1, sacc[nt], 0, 0, 0);
    }
    float p[4][4], mx[4];
#pragma unroll
    for (int r = 0; r < 4; ++r) {
      float m = -1e30f;
#pragma unroll
      for (int nt = 0; nt < 4; ++nt) {
        float s = (s0 + nt * 16 + l16 < len) ? sacc[nt][r] * 0.125f : -1e30f;
        p[nt][r] = s;
        m = fmaxf(m, s);
      }
      mx[r] = m;
    }
#pragma unroll
    for (int off = 1; off < 16; off <<= 1) {
#pragma unroll
      for (int r = 0; r < 4; ++r) mx[r] = fmaxf(mx[r], __shfl_xor(mx[r], off, 64));
    }
    float corr[4], rs[4];
#pragma unroll
    for (int r = 0; r < 4; ++r) {
      float mnew = fmaxf(mrun[r], mx[r]);
      corr[r] = __expf(mrun[r] - mnew);
      mrun[r] = mnew;
      float s = 0.f;
#pragma unroll
      for (int nt = 0; nt < 4; ++nt) {
        float e = __expf(p[nt][r] - mnew);
        p[nt][r] = e;
        s += e;
      }
      rs[r] = s;
    }
#pragma unroll
    for (int off = 1; off < 16; off <<= 1) {
#pragma unroll
      for (int r = 0; r < 4; ++r) rs[r] += __shfl_xor(rs[r], off, 64);
    }
#pragma unroll
    for (int r = 0; r < 4; ++r) {
      lrun[r] = lrun[r] * corr[r] + rs[r];
#pragma unroll
      for (int nt = 0; nt < 4; ++nt) {
        oacc[nt][r] *= corr[r];
        Ps[w][(quad * 4 + r) * 72 + nt * 16 + l16] = f2bf(p[nt][r]);
      }
    }
    short8 pf0 = *(const short8*)&Ps[w][l16 * 72 + quad * 8];
    short8 pf1 = *(const short8*)&Ps[w][l16 * 72 + 32 + quad * 8];
#pragma unroll
    for (int nt = 0; nt < 4; ++nt) {
      short8 vf0 = *(const short8*)&Vt[(nt * 16 + l16) * 72 + quad * 8];
      short8 vf1 = *(const short8*)&Vt[(nt * 16 + l16) * 72 + 32 + quad * 8];
      oacc[nt] = __builtin_amdgcn_mfma_f32_16x16x32_bf16(pf0, vf0, oacc[nt], 0, 0, 0);
      oacc[nt] = __builtin_amdgcn_mfma_f32_16x16x32_bf16(pf1, vf1, oacc[nt], 0, 0, 0);
    }
  }
#pragma unroll
  for (int r = 0; r < 4; ++r) {
    int t = tile * 64 + w * 16 + quad * 4 + r;
    float inv = (t < len) ? 1.f / lrun[r] : 0.f;
    ushort_t* op = o + ((size_t)(b * TT + t)) * DD + h * HSZ + l16;
#pragma unroll
    for (int nt = 0; nt < 4; ++nt) op[nt * 16] = f2bf(oacc[nt][r] * inv);
  }
}

// ---------------- attention pooling (per batch), fp32 in ----------------
__global__ __launch_bounds__(256) void k_pool(const float* __restrict__ xn,
                                              const int* __restrict__ lengths,
                                              const float* __restrict__ attn_w,
                                              const float* __restrict__ attn_b,
                                              float* __restrict__ summary) {
  __shared__ __align__(16) float sw[DD];
  __shared__ float sc[TT];
  __shared__ float red[8];
  int tid = threadIdx.x, b = blockIdx.x;
  int len = lengths[b];
  for (int i = tid; i < DD; i += 256) sw[i] = attn_w[i];
  __syncthreads();
  const float* xb = xn + (size_t)b * TT * DD;
  float ab = attn_b[0];
  for (int t = tid; t < TT; t += 256) {
    const float4* xr = (const float4*)(xb + (size_t)t * DD);
    const float4* wr = (const float4*)sw;
    float s = 0.f;
    for (int d = 0; d < DD / 4; ++d) {
      float4 xv = xr[d], wv = wr[d];
      s += xv.x * wv.x + xv.y * wv.y + xv.z * wv.z + xv.w * wv.w;
    }
    sc[t] = s + ab;
  }
  __syncthreads();
  float m = -1e30f;
  for (int t = tid; t < len; t += 256) m = fmaxf(m, sc[t]);
#pragma unroll
  for (int off = 32; off; off >>= 1) m = fmaxf(m, __shfl_down(m, off, 64));
  if ((tid & 63) == 0) red[tid >> 6] = m;
  __syncthreads();
  m = fmaxf(fmaxf(red[0], red[1]), fmaxf(red[2], red[3]));
  float ssum = 0.f;
  for (int t = tid; t < len; t += 256) ssum += __expf(sc[t] - m);
#pragma unroll
  for (int off = 32; off; off >>= 1) ssum += __shfl_down(ssum, off, 64);
  if ((tid & 63) == 0) red[4 + (tid >> 6)] = ssum;
  __syncthreads();
  float inv = 1.f / (red[4] + red[5] + red[6] + red[7]);
  __syncthreads();
  for (int t = tid; t < TT; t += 256) sc[t] = (t < len) ? __expf(sc[t] - m) * inv : 0.f;
  __syncthreads();
  for (int d = tid; d < DD; d += 256) {
    float acc = 0.f;
    for (int t = 0; t < TT; ++t) acc += sc[t] * xb[(size_t)t * DD + d];
    summary[b * DD + d] = acc;
  }
}

// ---------------- classification head ----------------
__global__ __launch_bounds__(64) void k_head(const float* __restrict__ summary,
                                             const float* __restrict__ head_w,
                                             const float* __restrict__ head_b,
                                             float* __restrict__ out) {
  int b = blockIdx.x, j = threadIdx.x;
  if (j < 49) {
    float s = head_b[j];
    for (int d = 0; d < DD; ++d) s += summary[b * DD + d] * head_w[d * 49 + j];
    out[b * 49 + j] = s;
  }
}

extern "C" void kernel_launch(void* const* d_in, const int* in_sizes, int n_in,
                              void* d_out, int out_size, void* d_ws, size_t ws_size,
                              hipStream_t stream) {
  const int* code = (const int*)d_in[0];
  const int* lengths = (const int*)d_in[1];
  const float* emb = (const float*)d_in[2];
  const float* Wq = (const float*)d_in[3];
  const float* Wk = (const float*)d_in[4];
  const float* Wv = (const float*)d_in[5];
  const float* Wo = (const float*)d_in[6];
  const float* bo = (const float*)d_in[7];
  const float* W1 = (const float*)d_in[8];
  const float* b1 = (const float*)d_in[9];
  const float* W2 = (const float*)d_in[10];
  const float* b2 = (const float*)d_in[11];
  const float* ln1_g = (const float*)d_in[12];
  const float* ln1_b = (const float*)d_in[13];
  const float* ln2_g = (const float*)d_in[14];
  const float* ln2_b = (const float*)d_in[15];
  const float* lnf_g = (const float*)d_in[16];
  const float* lnf_b = (const float*)d_in[17];
  const float* attn_w = (const float*)d_in[18];
  const float* attn_b = (const float*)d_in[19];
  const float* head_w = (const float*)d_in[20];
  const float* head_b = (const float*)d_in[21];
  float* out = (float*)d_out;

  const size_t NTOK = (size_t)BB * TT;  // 8192
  float* x = (float*)d_ws;                       // 8192*512 fp32
  ushort_t* xn = (ushort_t*)(x + NTOK * DD);     // 8192*512 bf16
  ushort_t* un = xn + NTOK * DD;                 // union: qkv | h1 | xf
  ushort_t* qkv = un;
  ushort_t* h1 = un;
  float* xf = (float*)un;
  ushort_t* wqt = un + (size_t)NTOK * FF4;
  ushort_t* wot = wqt + (size_t)LL * 1536 * 512;
  ushort_t* w1t = wot + (size_t)LL * 512 * 512;
  ushort_t* w2t = w1t + (size_t)LL * 512 * FF4;
  float* summary = (float*)(w2t + (size_t)LL * FF4 * 512);

  k_transpose<<<dim3(8, 1, 48), 256, 0, stream>>>(Wq, wqt,             64, (long)512 * 64, 8, (long)1536 * 512, (long)64 * 512, 512);
  k_transpose<<<dim3(8, 1, 48), 256, 0, stream>>>(Wk, wqt + 512 * 512,  64, (long)512 * 64, 8, (long)1536 * 512, (long)64 * 512, 512);
  k_transpose<<<dim3(8, 1, 48), 256, 0, stream>>>(Wv, wqt + 1024 * 512, 64, (long)512 * 64, 8, (long)1536 * 512, (long)64 * 512, 512);
  k_transpose<<<dim3(8, 8, 6), 256, 0, stream>>>(Wo, wot, 512, (long)512 * 512, 1, (long)512 * 512, 0, 512);
  k_transpose<<<dim3(8, 32, 6), 256, 0, stream>>>(W1, w1t, 2048, (long)512 * 2048, 1, (long)2048 * 512, 0, 512);
  k_transpose<<<dim3(32, 8, 6), 256, 0, stream>>>(W2, w2t, 512, (long)2048 * 512, 1, (long)512 * 2048, 0, 2048);

  k_embed<<<dim3((unsigned)((NTOK * DD) / 256)), dim3(256), 0, stream>>>(code, emb, x);

  for (int l = 0; l < LL; ++l) {
    k_ln<<<dim3(NTOK / 4), 256, 0, stream>>>(x, xn, nullptr, ln1_g + l * DD, ln1_b + l * DD);
    k_gemm<<<dim3(12, 64), 256, 0, stream>>>(xn, wqt + (size_t)l * 1536 * 512, nullptr, nullptr,
                                             nullptr, qkv, (int)NTOK, 1536, 512, 0);
    k_attn<<<dim3(BB * HH * (TT / 64)), 256, 0, stream>>>(qkv, lengths, xn);
    // Wo + residual: 64x128 tiles -> 512 blocks (2/CU)
    k_gemm64<<<dim3(4, 128), 256, 0, stream>>>(xn, wot + (size_t)l * 512 * 512, x, bo + l * DD,
                                               x, nullptr, (int)NTOK, 512, 512, 0);
    k_ln<<<dim3(NTOK / 4), 256, 0, stream>>>(x, xn, nullptr, ln2_g + l * DD, ln2_b + l * DD);
    k_gemm<<<dim3(16, 64), 256, 0, stream>>>(xn, w1t + (size_t)l * 512 * FF4, nullptr, b1 + l * FF4,
                                             nullptr, h1, (int)NTOK, FF4, 512, 1);
    // W2 + residual: 64x128 tiles -> 512 blocks (2/CU)
    k_gemm64<<<dim3(4, 128), 256, 0, stream>>>(h1, w2t + (size_t)l * FF4 * 512, x, b2 + l * DD,
                                               x, nullptr, (int)NTOK, 512, FF4, 0);
  }
  k_ln<<<dim3(NTOK / 4), 256, 0, stream>>>(x, nullptr, xf, lnf_g, lnf_b);
  k_pool<<<dim3(BB), 256, 0, stream>>>(xf, lengths, attn_w, attn_b, summary);
  k_head<<<dim3(BB), 64, 0, stream>>>(summary, head_w, head_b, out);
}

// Round 5
// 1881.283 us; speedup vs baseline: 5.6272x; 1.0261x over previous
//
#include <hip/hip_runtime.h>
#include <math.h>

#define TT 1024
#define BB 8
#define DD 512
#define HH 8
#define HSZ 64
#define LL 6
#define FF4 2048

typedef __attribute__((ext_vector_type(8))) short short8;
typedef __attribute__((ext_vector_type(4))) float floatx4;
typedef unsigned short ushort_t;
typedef unsigned int uint_t;

__device__ __forceinline__ ushort_t f2bf(float f) {
  uint_t u = __float_as_uint(f);
  u += 0x7fff + ((u >> 16) & 1);  // RNE
  return (ushort_t)(u >> 16);
}
__device__ __forceinline__ float bf2f(ushort_t h) {
  return __uint_as_float(((uint_t)h) << 16);
}

__device__ __forceinline__ void gload16(const void* g, void* l) {
  __builtin_amdgcn_global_load_lds((const __attribute__((address_space(1))) void*)g,
                                   (__attribute__((address_space(3))) void*)l, 16, 0, 0);
}

// ---------------- embed + positional encoding ----------------
__global__ __launch_bounds__(256) void k_embed(const int* __restrict__ code,
                                               const float* __restrict__ emb,
                                               float* __restrict__ x) {
  int idx = blockIdx.x * 256 + threadIdx.x;  // over B*T*D
  int c = idx & (DD - 1);
  int bt = idx >> 9;
  int t = bt & (TT - 1);
  int f = c >> 4, e = c & 15;
  int vv = code[bt * 32 + f];
  int i = c >> 1;
  float freq = expf((float)(2 * i) * (-9.210340371976184f / 512.f));
  float ang = (float)t * freq;
  float pe = (c & 1) ? cosf(ang) : sinf(ang);
  x[idx] = emb[vv * 16 + e] + pe;
}

// ---------------- layernorm (+ optional fused attention-pool score) ----------------
__global__ __launch_bounds__(256) void k_ln(const float* __restrict__ x,
                                            ushort_t* __restrict__ yB,
                                            float* __restrict__ yF,
                                            const float* __restrict__ g,
                                            const float* __restrict__ b,
                                            const float* __restrict__ aw,
                                            const float* __restrict__ ab,
                                            float* __restrict__ scores) {
  int wave = threadIdx.x >> 6, lane = threadIdx.x & 63;
  int row = blockIdx.x * 4 + wave;
  const float* xr = x + (size_t)row * DD;
  float v[8];
  float s = 0.f;
#pragma unroll
  for (int j = 0; j < 8; ++j) { v[j] = xr[lane + 64 * j]; s += v[j]; }
#pragma unroll
  for (int off = 32; off; off >>= 1) s += __shfl_down(s, off, 64);
  float mean = __shfl(s, 0, 64) * (1.f / DD);
  float qv = 0.f;
#pragma unroll
  for (int j = 0; j < 8; ++j) { float d = v[j] - mean; qv += d * d; }
#pragma unroll
  for (int off = 32; off; off >>= 1) qv += __shfl_down(qv, off, 64);
  float rs = rsqrtf(__shfl(qv, 0, 64) * (1.f / DD) + 1e-5f);
  float sdot = 0.f;
#pragma unroll
  for (int j = 0; j < 8; ++j) {
    int c = lane + 64 * j;
    float val = (v[j] - mean) * rs * g[c] + b[c];
    if (yB) yB[(size_t)row * DD + c] = f2bf(val);
    else    yF[(size_t)row * DD + c] = val;
    if (scores) sdot += val * aw[c];
  }
  if (scores) {
#pragma unroll
    for (int off = 32; off; off >>= 1) sdot += __shfl_down(sdot, off, 64);
    if (lane == 0) scores[row] = sdot + ab[0];
  }
}

// ---------------- fp32 -> bf16 transposed weight prep ----------------
__global__ __launch_bounds__(256) void k_transpose(const float* __restrict__ in,
                                                   ushort_t* __restrict__ out,
                                                   int Nin, long in_ms, int nh,
                                                   long os_l, long os_h, int out_ld) {
  __shared__ float t4[64][65];
  int mz = blockIdx.z;
  const float* ip = in + (size_t)mz * in_ms;
  ushort_t* op = out + (size_t)(mz / nh) * os_l + (size_t)(mz % nh) * os_h;
  int k0 = blockIdx.x * 64, n0 = blockIdx.y * 64;
  int c = threadIdx.x & 63, r0 = threadIdx.x >> 6;
#pragma unroll
  for (int i = 0; i < 16; ++i) {
    int r = r0 * 16 + i;
    t4[r][c] = ip[(size_t)(k0 + r) * Nin + n0 + c];
  }
  __syncthreads();
#pragma unroll
  for (int i = 0; i < 16; ++i) {
    int n = r0 * 16 + i;
    op[(size_t)(n0 + n) * out_ld + k0 + c] = f2bf(t4[c][n]);
  }
}

// ---------------- bf16 MFMA GEMM, 128x128 tile, BK=64 ----------------
// LDS slots (16B each): A slot(kc,m) = A[row0+m][k0+kc*8..+8], kc=0..7, m=0..127;
// B likewise at +8192 shorts. 2 barriers per 64 K (half of BK=32).
__global__ __launch_bounds__(256) void k_gemm(const ushort_t* __restrict__ A,
                                              const ushort_t* __restrict__ Bt,
                                              const float* __restrict__ resid,
                                              const float* __restrict__ bias,
                                              float* __restrict__ outF,
                                              ushort_t* __restrict__ outB,
                                              int M, int N, int K, int dogelu) {
  __shared__ short lds[16384];
  const int tid = threadIdx.x;
  const int w = tid >> 6, lane = tid & 63;
  const int quad = lane >> 4, l16 = lane & 15;
  const int wm = w >> 1, wn = w & 1;
  const int row0 = blockIdx.y * 128, col0 = blockIdx.x * 128;
  const short* Ag = (const short*)A + (size_t)(row0 + lane) * K + w * 8;
  const short* Bg = (const short*)Bt + (size_t)(col0 + lane) * K + w * 8;
  floatx4 acc[4][4] = {};
  for (int k0 = 0; k0 < K; k0 += 64) {
    // wave w stages kc=w (k0+w*8) and kc=w+4 (k0+32+w*8), rows lane & lane+64
    gload16(Ag + k0, &lds[(w * 128) * 8]);
    gload16(Ag + k0 + (size_t)64 * K, &lds[(w * 128 + 64) * 8]);
    gload16(Ag + k0 + 32, &lds[((w + 4) * 128) * 8]);
    gload16(Ag + k0 + 32 + (size_t)64 * K, &lds[((w + 4) * 128 + 64) * 8]);
    gload16(Bg + k0, &lds[8192 + (w * 128) * 8]);
    gload16(Bg + k0 + (size_t)64 * K, &lds[8192 + (w * 128 + 64) * 8]);
    gload16(Bg + k0 + 32, &lds[8192 + ((w + 4) * 128) * 8]);
    gload16(Bg + k0 + 32 + (size_t)64 * K, &lds[8192 + ((w + 4) * 128 + 64) * 8]);
    __syncthreads();
#pragma unroll
    for (int c = 0; c < 2; ++c) {
      const int kc = c * 4 + quad;
      short8 af[4], bfr[4];
#pragma unroll
      for (int mt = 0; mt < 4; ++mt)
        af[mt] = *(const short8*)&lds[(kc * 128 + wm * 64 + mt * 16 + l16) * 8];
#pragma unroll
      for (int nt = 0; nt < 4; ++nt)
        bfr[nt] = *(const short8*)&lds[8192 + (kc * 128 + wn * 64 + nt * 16 + l16) * 8];
#pragma unroll
      for (int mt = 0; mt < 4; ++mt)
#pragma unroll
        for (int nt = 0; nt < 4; ++nt)
          acc[mt][nt] = __builtin_amdgcn_mfma_f32_16x16x32_bf16(af[mt], bfr[nt], acc[mt][nt], 0, 0, 0);
    }
    __syncthreads();
  }
  const int mb = row0 + wm * 64 + quad * 4;
  const int nb = col0 + wn * 64 + l16;
#pragma unroll
  for (int mt = 0; mt < 4; ++mt) {
#pragma unroll
    for (int nt = 0; nt < 4; ++nt) {
      floatx4 a4 = acc[mt][nt];
#pragma unroll
      for (int r = 0; r < 4; ++r) {
        int row = mb + mt * 16 + r;
        int col = nb + nt * 16;
        float val = a4[r];
        if (bias) val += bias[col];
        if (dogelu) val = 0.5f * val * (1.f + erff(val * 0.7071067811865475f));
        size_t idx = (size_t)row * N + col;
        if (resid) val += resid[idx];
        if (outF) outF[idx] = val;
        else outB[idx] = f2bf(val);
      }
    }
  }
}

// ---------------- bf16 MFMA GEMM, 64x128 tile, BK=64 (N=512: 2 blocks/CU) ----------------
// XCD swizzle: the 4 column blocks of one row-block land on one XCD.
__global__ __launch_bounds__(256) void k_gemm64(const ushort_t* __restrict__ A,
                                                const ushort_t* __restrict__ Bt,
                                                const float* __restrict__ resid,
                                                const float* __restrict__ bias,
                                                float* __restrict__ outF,
                                                ushort_t* __restrict__ outB,
                                                int M, int N, int K, int dogelu) {
  __shared__ short lds[12288];  // A 64x64 (4096 sh) + B 128x64 (8192 sh)
  const int tid = threadIdx.x;
  const int w = tid >> 6, lane = tid & 63;
  const int quad = lane >> 4, l16 = lane & 15;
  const int wm = w >> 1, wn = w & 1;
  int bx, by;
  if (gridDim.x == 4 && (gridDim.y & 7) == 0) {
    int id = blockIdx.y * 4 + blockIdx.x;
    bx = (id >> 3) & 3;
    by = ((id >> 5) << 3) | (id & 7);
  } else {
    bx = blockIdx.x; by = blockIdx.y;
  }
  const int row0 = by * 64, col0 = bx * 128;
  const short* Ag = (const short*)A + (size_t)(row0 + lane) * K + w * 8;
  const short* Bg = (const short*)Bt + (size_t)(col0 + lane) * K + w * 8;
  floatx4 acc[2][4] = {};
  for (int k0 = 0; k0 < K; k0 += 64) {
    gload16(Ag + k0, &lds[(w * 64) * 8]);
    gload16(Ag + k0 + 32, &lds[((w + 4) * 64) * 8]);
    gload16(Bg + k0, &lds[4096 + (w * 128) * 8]);
    gload16(Bg + k0 + (size_t)64 * K, &lds[4096 + (w * 128 + 64) * 8]);
    gload16(Bg + k0 + 32, &lds[4096 + ((w + 4) * 128) * 8]);
    gload16(Bg + k0 + 32 + (size_t)64 * K, &lds[4096 + ((w + 4) * 128 + 64) * 8]);
    __syncthreads();
#pragma unroll
    for (int c = 0; c < 2; ++c) {
      const int kc = c * 4 + quad;
      short8 af[2], bfr[4];
#pragma unroll
      for (int mt = 0; mt < 2; ++mt)
        af[mt] = *(const short8*)&lds[(kc * 64 + wm * 32 + mt * 16 + l16) * 8];
#pragma unroll
      for (int nt = 0; nt < 4; ++nt)
        bfr[nt] = *(const short8*)&lds[4096 + (kc * 128 + wn * 64 + nt * 16 + l16) * 8];
#pragma unroll
      for (int mt = 0; mt < 2; ++mt)
#pragma unroll
        for (int nt = 0; nt < 4; ++nt)
          acc[mt][nt] = __builtin_amdgcn_mfma_f32_16x16x32_bf16(af[mt], bfr[nt], acc[mt][nt], 0, 0, 0);
    }
    __syncthreads();
  }
  const int mb = row0 + wm * 32 + quad * 4;
  const int nb = col0 + wn * 64 + l16;
#pragma unroll
  for (int mt = 0; mt < 2; ++mt) {
#pragma unroll
    for (int nt = 0; nt < 4; ++nt) {
      floatx4 a4 = acc[mt][nt];
#pragma unroll
      for (int r = 0; r < 4; ++r) {
        int row = mb + mt * 16 + r;
        int col = nb + nt * 16;
        float val = a4[r];
        if (bias) val += bias[col];
        if (dogelu) val = 0.5f * val * (1.f + erff(val * 0.7071067811865475f));
        size_t idx = (size_t)row * N + col;
        if (resid) val += resid[idx];
        if (outF) outF[idx] = val;
        else outB[idx] = f2bf(val);
      }
    }
  }
}

// ---------------- MFMA flash attention ----------------
__global__ __launch_bounds__(256) void k_attn(const ushort_t* __restrict__ qkv,
                                              const int* __restrict__ lengths,
                                              ushort_t* __restrict__ o) {
  __shared__ ushort_t Ks[64 * 72];
  __shared__ ushort_t Vt[64 * 72];
  __shared__ ushort_t Ps[4][16 * 72];
  const int tid = threadIdx.x;
  const int w = tid >> 6, lane = tid & 63;
  const int quad = lane >> 4, l16 = lane & 15;
  const int tile = blockIdx.x & 15;
  const int bh = blockIdx.x >> 4;
  const int b = bh >> 3, h = bh & 7;
  const int len = lengths[b];
  const int tqa = tile * 64 + w * 16 + l16;
  const ushort_t* qp = qkv + ((size_t)(b * TT + tqa)) * 1536 + h * HSZ + quad * 8;
  short8 qf0 = *(const short8*)qp;
  short8 qf1 = *(const short8*)(qp + 32);
  floatx4 oacc[4] = {};
  float mrun[4], lrun[4];
#pragma unroll
  for (int r = 0; r < 4; ++r) { mrun[r] = -1e30f; lrun[r] = 0.f; }
  const int skey = tid >> 2, sseg = (tid & 3) << 4;
  const int vkp = (tid & 31) << 1, vds = (tid >> 5) << 3;
  const int nkt = (len + 63) >> 6;
  for (int kt = 0; kt < nkt; ++kt) {
    const int s0 = kt * 64;
    __syncthreads();
    {
      const ushort_t* kp = qkv + ((size_t)(b * TT + s0 + skey)) * 1536 + 512 + h * HSZ + sseg;
      short8 k0 = *(const short8*)kp;
      short8 k1 = *(const short8*)(kp + 8);
      *(short8*)&Ks[skey * 72 + sseg] = k0;
      *(short8*)&Ks[skey * 72 + sseg + 8] = k1;
      const ushort_t* vp0 = qkv + ((size_t)(b * TT + s0 + vkp)) * 1536 + 1024 + h * HSZ + vds;
      short8 v0 = *(const short8*)vp0;
      short8 v1 = *(const short8*)(vp0 + 1536);
#pragma unroll
      for (int i = 0; i < 8; ++i) {
        ushort2 pr;
        pr.x = (ushort_t)v0[i];
        pr.y = (ushort_t)v1[i];
        *(ushort2*)&Vt[(vds + i) * 72 + vkp] = pr;
      }
    }
    __syncthreads();
    floatx4 sacc[4] = {};
#pragma unroll
    for (int nt = 0; nt < 4; ++nt) {
      short8 kf0 = *(const short8*)&Ks[(nt * 16 + l16) * 72 + quad * 8];
      short8 kf1 = *(const short8*)&Ks[(nt * 16 + l16) * 72 + 32 + quad * 8];
      sacc[nt] = __builtin_amdgcn_mfma_f32_16x16x32_bf16(qf0, kf0, sacc[nt], 0, 0, 0);
      sacc[nt] = __builtin_amdgcn_mfma_f32_16x16x32_bf16(qf1, kf1, sacc[nt], 0, 0, 0);
    }
    float p[4][4], mx[4];
#pragma unroll
    for (int r = 0; r < 4; ++r) {
      float m = -1e30f;
#pragma unroll
      for (int nt = 0; nt < 4; ++nt) {
        float s = (s0 + nt * 16 + l16 < len) ? sacc[nt][r] * 0.125f : -1e30f;
        p[nt][r] = s;
        m = fmaxf(m, s);
      }
      mx[r] = m;
    }
#pragma unroll
    for (int off = 1; off < 16; off <<= 1) {
#pragma unroll
      for (int r = 0; r < 4; ++r) mx[r] = fmaxf(mx[r], __shfl_xor(mx[r], off, 64));
    }
    float corr[4], rs[4];
#pragma unroll
    for (int r = 0; r < 4; ++r) {
      float mnew = fmaxf(mrun[r], mx[r]);
      corr[r] = __expf(mrun[r] - mnew);
      mrun[r] = mnew;
      float s = 0.f;
#pragma unroll
      for (int nt = 0; nt < 4; ++nt) {
        float e = __expf(p[nt][r] - mnew);
        p[nt][r] = e;
        s += e;
      }
      rs[r] = s;
    }
#pragma unroll
    for (int off = 1; off < 16; off <<= 1) {
#pragma unroll
      for (int r = 0; r < 4; ++r) rs[r] += __shfl_xor(rs[r], off, 64);
    }
#pragma unroll
    for (int r = 0; r < 4; ++r) {
      lrun[r] = lrun[r] * corr[r] + rs[r];
#pragma unroll
      for (int nt = 0; nt < 4; ++nt) {
        oacc[nt][r] *= corr[r];
        Ps[w][(quad * 4 + r) * 72 + nt * 16 + l16] = f2bf(p[nt][r]);
      }
    }
    short8 pf0 = *(const short8*)&Ps[w][l16 * 72 + quad * 8];
    short8 pf1 = *(const short8*)&Ps[w][l16 * 72 + 32 + quad * 8];
#pragma unroll
    for (int nt = 0; nt < 4; ++nt) {
      short8 vf0 = *(const short8*)&Vt[(nt * 16 + l16) * 72 + quad * 8];
      short8 vf1 = *(const short8*)&Vt[(nt * 16 + l16) * 72 + 32 + quad * 8];
      oacc[nt] = __builtin_amdgcn_mfma_f32_16x16x32_bf16(pf0, vf0, oacc[nt], 0, 0, 0);
      oacc[nt] = __builtin_amdgcn_mfma_f32_16x16x32_bf16(pf1, vf1, oacc[nt], 0, 0, 0);
    }
  }
#pragma unroll
  for (int r = 0; r < 4; ++r) {
    int t = tile * 64 + w * 16 + quad * 4 + r;
    float inv = (t < len) ? 1.f / lrun[r] : 0.f;
    ushort_t* op = o + ((size_t)(b * TT + t)) * DD + h * HSZ + l16;
#pragma unroll
    for (int nt = 0; nt < 4; ++nt) op[nt * 16] = f2bf(oacc[nt][r] * inv);
  }
}

// ---------------- pool softmax: scores -> weights (per batch) ----------------
__global__ __launch_bounds__(256) void k_softw(const float* __restrict__ scores,
                                               const int* __restrict__ lengths,
                                               float* __restrict__ wts) {
  __shared__ float red[8];
  int tid = threadIdx.x, b = blockIdx.x;
  int len = lengths[b];
  const float* sb = scores + b * TT;
  float m = -1e30f;
  for (int t = tid; t < len; t += 256) m = fmaxf(m, sb[t]);
#pragma unroll
  for (int off = 32; off; off >>= 1) m = fmaxf(m, __shfl_down(m, off, 64));
  if ((tid & 63) == 0) red[tid >> 6] = m;
  __syncthreads();
  m = fmaxf(fmaxf(red[0], red[1]), fmaxf(red[2], red[3]));
  float ssum = 0.f;
  for (int t = tid; t < len; t += 256) ssum += __expf(sb[t] - m);
#pragma unroll
  for (int off = 32; off; off >>= 1) ssum += __shfl_down(ssum, off, 64);
  if ((tid & 63) == 0) red[4 + (tid >> 6)] = ssum;
  __syncthreads();
  float inv = 1.f / (red[4] + red[5] + red[6] + red[7]);
  for (int t = tid; t < TT; t += 256)
    wts[b * TT + t] = (t < len) ? __expf(sb[t] - m) * inv : 0.f;
}

// ---------------- weighted sum partials: grid (B, 16), 64 rows each ----------------
__global__ __launch_bounds__(256) void k_wsum(const float* __restrict__ xf,
                                              const float* __restrict__ wts,
                                              float* __restrict__ partial) {
  int b = blockIdx.x, c = blockIdx.y, tid = threadIdx.x;
  const float* xb = xf + ((size_t)b * TT + c * 64) * DD;
  const float* wb = wts + b * TT + c * 64;
  float a0 = 0.f, a1 = 0.f;
  for (int t = 0; t < 64; ++t) {
    float wv = wb[t];
    a0 += wv * xb[(size_t)t * DD + tid];
    a1 += wv * xb[(size_t)t * DD + tid + 256];
  }
  float* pp = partial + ((size_t)b * 16 + c) * DD;
  pp[tid] = a0;
  pp[tid + 256] = a1;
}

// ---------------- classification head (reduces the 16 partials) ----------------
__global__ __launch_bounds__(64) void k_head(const float* __restrict__ partial,
                                             const float* __restrict__ head_w,
                                             const float* __restrict__ head_b,
                                             float* __restrict__ out) {
  __shared__ float ssum[DD];
  int b = blockIdx.x, tid = threadIdx.x;
  for (int d = tid; d < DD; d += 64) {
    float s = 0.f;
#pragma unroll
    for (int c = 0; c < 16; ++c) s += partial[((size_t)b * 16 + c) * DD + d];
    ssum[d] = s;
  }
  __syncthreads();
  if (tid < 49) {
    float s = head_b[tid];
    for (int d = 0; d < DD; ++d) s += ssum[d] * head_w[d * 49 + tid];
    out[b * 49 + tid] = s;
  }
}

extern "C" void kernel_launch(void* const* d_in, const int* in_sizes, int n_in,
                              void* d_out, int out_size, void* d_ws, size_t ws_size,
                              hipStream_t stream) {
  const int* code = (const int*)d_in[0];
  const int* lengths = (const int*)d_in[1];
  const float* emb = (const float*)d_in[2];
  const float* Wq = (const float*)d_in[3];
  const float* Wk = (const float*)d_in[4];
  const float* Wv = (const float*)d_in[5];
  const float* Wo = (const float*)d_in[6];
  const float* bo = (const float*)d_in[7];
  const float* W1 = (const float*)d_in[8];
  const float* b1 = (const float*)d_in[9];
  const float* W2 = (const float*)d_in[10];
  const float* b2 = (const float*)d_in[11];
  const float* ln1_g = (const float*)d_in[12];
  const float* ln1_b = (const float*)d_in[13];
  const float* ln2_g = (const float*)d_in[14];
  const float* ln2_b = (const float*)d_in[15];
  const float* lnf_g = (const float*)d_in[16];
  const float* lnf_b = (const float*)d_in[17];
  const float* attn_w = (const float*)d_in[18];
  const float* attn_b = (const float*)d_in[19];
  const float* head_w = (const float*)d_in[20];
  const float* head_b = (const float*)d_in[21];
  float* out = (float*)d_out;

  const size_t NTOK = (size_t)BB * TT;  // 8192
  float* x = (float*)d_ws;                       // 8192*512 fp32
  ushort_t* xn = (ushort_t*)(x + NTOK * DD);     // 8192*512 bf16
  ushort_t* un = xn + NTOK * DD;                 // union: qkv | h1 | xf
  ushort_t* qkv = un;
  ushort_t* h1 = un;
  float* xf = (float*)un;
  ushort_t* wqt = un + (size_t)NTOK * FF4;
  ushort_t* wot = wqt + (size_t)LL * 1536 * 512;
  ushort_t* w1t = wot + (size_t)LL * 512 * 512;
  ushort_t* w2t = w1t + (size_t)LL * 512 * FF4;
  float* scores = (float*)(w2t + (size_t)LL * FF4 * 512);  // 8192
  float* wts = scores + NTOK;                              // 8192
  float* partial = wts + NTOK;                             // 8*16*512

  k_transpose<<<dim3(8, 1, 48), 256, 0, stream>>>(Wq, wqt,             64, (long)512 * 64, 8, (long)1536 * 512, (long)64 * 512, 512);
  k_transpose<<<dim3(8, 1, 48), 256, 0, stream>>>(Wk, wqt + 512 * 512,  64, (long)512 * 64, 8, (long)1536 * 512, (long)64 * 512, 512);
  k_transpose<<<dim3(8, 1, 48), 256, 0, stream>>>(Wv, wqt + 1024 * 512, 64, (long)512 * 64, 8, (long)1536 * 512, (long)64 * 512, 512);
  k_transpose<<<dim3(8, 8, 6), 256, 0, stream>>>(Wo, wot, 512, (long)512 * 512, 1, (long)512 * 512, 0, 512);
  k_transpose<<<dim3(8, 32, 6), 256, 0, stream>>>(W1, w1t, 2048, (long)512 * 2048, 1, (long)2048 * 512, 0, 512);
  k_transpose<<<dim3(32, 8, 6), 256, 0, stream>>>(W2, w2t, 512, (long)2048 * 512, 1, (long)512 * 2048, 0, 2048);

  k_embed<<<dim3((unsigned)((NTOK * DD) / 256)), dim3(256), 0, stream>>>(code, emb, x);

  for (int l = 0; l < LL; ++l) {
    k_ln<<<dim3(NTOK / 4), 256, 0, stream>>>(x, xn, nullptr, ln1_g + l * DD, ln1_b + l * DD,
                                             nullptr, nullptr, nullptr);
    k_gemm<<<dim3(12, 64), 256, 0, stream>>>(xn, wqt + (size_t)l * 1536 * 512, nullptr, nullptr,
                                             nullptr, qkv, (int)NTOK, 1536, 512, 0);
    k_attn<<<dim3(BB * HH * (TT / 64)), 256, 0, stream>>>(qkv, lengths, xn);
    k_gemm64<<<dim3(4, 128), 256, 0, stream>>>(xn, wot + (size_t)l * 512 * 512, x, bo + l * DD,
                                               x, nullptr, (int)NTOK, 512, 512, 0);
    k_ln<<<dim3(NTOK / 4), 256, 0, stream>>>(x, xn, nullptr, ln2_g + l * DD, ln2_b + l * DD,
                                             nullptr, nullptr, nullptr);
    k_gemm<<<dim3(16, 64), 256, 0, stream>>>(xn, w1t + (size_t)l * 512 * FF4, nullptr, b1 + l * FF4,
                                             nullptr, h1, (int)NTOK, FF4, 512, 1);
    k_gemm64<<<dim3(4, 128), 256, 0, stream>>>(h1, w2t + (size_t)l * FF4 * 512, x, b2 + l * DD,
                                               x, nullptr, (int)NTOK, 512, FF4, 0);
  }
  k_ln<<<dim3(NTOK / 4), 256, 0, stream>>>(x, nullptr, xf, lnf_g, lnf_b,
                                           attn_w, attn_b, scores);
  k_softw<<<dim3(BB), 256, 0, stream>>>(scores, lengths, wts);
  k_wsum<<<dim3(BB, 16), 256, 0, stream>>>(xf, wts, partial);
  k_head<<<dim3(BB), 64, 0, stream>>>(partial, head_w, head_b, out);
}

// Round 6
// 1836.786 us; speedup vs baseline: 5.7635x; 1.0242x over previous
//
#include <hip/hip_runtime.h>
#include <math.h>

#define TT 1024
#define BB 8
#define DD 512
#define HH 8
#define HSZ 64
#define LL 6
#define FF4 2048

typedef __attribute__((ext_vector_type(8))) short short8;
typedef __attribute__((ext_vector_type(4))) float floatx4;
typedef unsigned short ushort_t;
typedef unsigned int uint_t;

__device__ __forceinline__ ushort_t f2bf(float f) {
  uint_t u = __float_as_uint(f);
  u += 0x7fff + ((u >> 16) & 1);  // RNE
  return (ushort_t)(u >> 16);
}
__device__ __forceinline__ float bf2f(ushort_t h) {
  return __uint_as_float(((uint_t)h) << 16);
}

__device__ __forceinline__ void gload16(const void* g, void* l) {
  __builtin_amdgcn_global_load_lds((const __attribute__((address_space(1))) void*)g,
                                   (__attribute__((address_space(3))) void*)l, 16, 0, 0);
}

// ---------------- embed + positional encoding ----------------
__global__ __launch_bounds__(256) void k_embed(const int* __restrict__ code,
                                               const float* __restrict__ emb,
                                               float* __restrict__ x) {
  int idx = blockIdx.x * 256 + threadIdx.x;  // over B*T*D
  int c = idx & (DD - 1);
  int bt = idx >> 9;
  int t = bt & (TT - 1);
  int f = c >> 4, e = c & 15;
  int vv = code[bt * 32 + f];
  int i = c >> 1;
  float freq = expf((float)(2 * i) * (-9.210340371976184f / 512.f));
  float ang = (float)t * freq;
  float pe = (c & 1) ? cosf(ang) : sinf(ang);
  x[idx] = emb[vv * 16 + e] + pe;
}

// ---------------- layernorm (+ optional fused attention-pool score) ----------------
__global__ __launch_bounds__(256) void k_ln(const float* __restrict__ x,
                                            ushort_t* __restrict__ yB,
                                            float* __restrict__ yF,
                                            const float* __restrict__ g,
                                            const float* __restrict__ b,
                                            const float* __restrict__ aw,
                                            const float* __restrict__ ab,
                                            float* __restrict__ scores) {
  int wave = threadIdx.x >> 6, lane = threadIdx.x & 63;
  int row = blockIdx.x * 4 + wave;
  const float* xr = x + (size_t)row * DD;
  float v[8];
  float s = 0.f;
#pragma unroll
  for (int j = 0; j < 8; ++j) { v[j] = xr[lane + 64 * j]; s += v[j]; }
#pragma unroll
  for (int off = 32; off; off >>= 1) s += __shfl_down(s, off, 64);
  float mean = __shfl(s, 0, 64) * (1.f / DD);
  float qv = 0.f;
#pragma unroll
  for (int j = 0; j < 8; ++j) { float d = v[j] - mean; qv += d * d; }
#pragma unroll
  for (int off = 32; off; off >>= 1) qv += __shfl_down(qv, off, 64);
  float rs = rsqrtf(__shfl(qv, 0, 64) * (1.f / DD) + 1e-5f);
  float sdot = 0.f;
#pragma unroll
  for (int j = 0; j < 8; ++j) {
    int c = lane + 64 * j;
    float val = (v[j] - mean) * rs * g[c] + b[c];
    if (yB) yB[(size_t)row * DD + c] = f2bf(val);
    else    yF[(size_t)row * DD + c] = val;
    if (scores) sdot += val * aw[c];
  }
  if (scores) {
#pragma unroll
    for (int off = 32; off; off >>= 1) sdot += __shfl_down(sdot, off, 64);
    if (lane == 0) scores[row] = sdot + ab[0];
  }
}

// ---------------- fp32 -> bf16 transposed weight prep ----------------
__global__ __launch_bounds__(256) void k_transpose(const float* __restrict__ in,
                                                   ushort_t* __restrict__ out,
                                                   int Nin, long in_ms, int nh,
                                                   long os_l, long os_h, int out_ld) {
  __shared__ float t4[64][65];
  int mz = blockIdx.z;
  const float* ip = in + (size_t)mz * in_ms;
  ushort_t* op = out + (size_t)(mz / nh) * os_l + (size_t)(mz % nh) * os_h;
  int k0 = blockIdx.x * 64, n0 = blockIdx.y * 64;
  int c = threadIdx.x & 63, r0 = threadIdx.x >> 6;
#pragma unroll
  for (int i = 0; i < 16; ++i) {
    int r = r0 * 16 + i;
    t4[r][c] = ip[(size_t)(k0 + r) * Nin + n0 + c];
  }
  __syncthreads();
#pragma unroll
  for (int i = 0; i < 16; ++i) {
    int n = r0 * 16 + i;
    op[(size_t)(n0 + n) * out_ld + k0 + c] = f2bf(t4[c][n]);
  }
}

// ---------------- bf16 MFMA GEMM, 128x128 tile, BK=32, single-barrier dbuf ----------------
// LDS buffer p (8192 shorts): A slot(kc,m)=(kc*128+m)*8, kc=0..3; B at +4096.
// Pipeline: stage(i+1) issued right after the barrier that publishes stage(i);
// the next barrier's vmcnt(0) drain happens after a full MFMA phase -> hidden.
__global__ __launch_bounds__(256) void k_gemm(const ushort_t* __restrict__ A,
                                              const ushort_t* __restrict__ Bt,
                                              const float* __restrict__ resid,
                                              const float* __restrict__ bias,
                                              float* __restrict__ outF,
                                              ushort_t* __restrict__ outB,
                                              int M, int N, int K, int dogelu) {
  __shared__ short lds[16384];
  const int tid = threadIdx.x;
  const int w = tid >> 6, lane = tid & 63;
  const int quad = lane >> 4, l16 = lane & 15;
  const int wm = w >> 1, wn = w & 1;
  const int row0 = blockIdx.y * 128, col0 = blockIdx.x * 128;
  const short* Ag = (const short*)A + (size_t)(row0 + lane) * K + w * 8;
  const short* Bg = (const short*)Bt + (size_t)(col0 + lane) * K + w * 8;
  floatx4 acc[4][4] = {};
  const int sA = (w * 128) * 8;
  const int sB = 4096 + (w * 128) * 8;
  // prologue stage into buf0
  {
    short* base = &lds[0];
    gload16(Ag, base + sA);
    gload16(Ag + (size_t)64 * K, base + sA + 512);
    gload16(Bg, base + sB);
    gload16(Bg + (size_t)64 * K, base + sB + 512);
  }
  const int nk = K >> 5;
  for (int i = 0; i < nk; ++i) {
    __syncthreads();  // publishes stage(i); drains its vmcnt (issued one MFMA-phase ago)
    if (i + 1 < nk) {
      const int k0 = (i + 1) << 5;
      short* base = &lds[((i + 1) & 1) * 8192];
      gload16(Ag + k0, base + sA);
      gload16(Ag + k0 + (size_t)64 * K, base + sA + 512);
      gload16(Bg + k0, base + sB);
      gload16(Bg + k0 + (size_t)64 * K, base + sB + 512);
    }
    const short* cur = &lds[(i & 1) * 8192];
    short8 af[4], bfr[4];
#pragma unroll
    for (int mt = 0; mt < 4; ++mt)
      af[mt] = *(const short8*)&cur[(quad * 128 + wm * 64 + mt * 16 + l16) * 8];
#pragma unroll
    for (int nt = 0; nt < 4; ++nt)
      bfr[nt] = *(const short8*)&cur[4096 + (quad * 128 + wn * 64 + nt * 16 + l16) * 8];
#pragma unroll
    for (int mt = 0; mt < 4; ++mt)
#pragma unroll
      for (int nt = 0; nt < 4; ++nt)
        acc[mt][nt] = __builtin_amdgcn_mfma_f32_16x16x32_bf16(af[mt], bfr[nt], acc[mt][nt], 0, 0, 0);
  }
  const int mb = row0 + wm * 64 + quad * 4;
  const int nb = col0 + wn * 64 + l16;
#pragma unroll
  for (int mt = 0; mt < 4; ++mt) {
#pragma unroll
    for (int nt = 0; nt < 4; ++nt) {
      floatx4 a4 = acc[mt][nt];
#pragma unroll
      for (int r = 0; r < 4; ++r) {
        int row = mb + mt * 16 + r;
        int col = nb + nt * 16;
        float val = a4[r];
        if (bias) val += bias[col];
        if (dogelu) val = 0.5f * val * (1.f + erff(val * 0.7071067811865475f));
        size_t idx = (size_t)row * N + col;
        if (resid) val += resid[idx];
        if (outF) outF[idx] = val;
        else outB[idx] = f2bf(val);
      }
    }
  }
}

// ---------------- bf16 MFMA GEMM, 64x128 tile, BK=32, single-barrier dbuf ----------------
// XCD swizzle: the 4 column blocks of one row-block land on one XCD.
// LDS buffer p (6144 shorts): A slot(kc,m)=(kc*64+m)*8; B at +2048.
__global__ __launch_bounds__(256) void k_gemm64(const ushort_t* __restrict__ A,
                                                const ushort_t* __restrict__ Bt,
                                                const float* __restrict__ resid,
                                                const float* __restrict__ bias,
                                                float* __restrict__ outF,
                                                ushort_t* __restrict__ outB,
                                                int M, int N, int K, int dogelu) {
  __shared__ short lds[12288];
  const int tid = threadIdx.x;
  const int w = tid >> 6, lane = tid & 63;
  const int quad = lane >> 4, l16 = lane & 15;
  const int wm = w >> 1, wn = w & 1;
  int bx, by;
  if (gridDim.x == 4 && (gridDim.y & 7) == 0) {
    int id = blockIdx.y * 4 + blockIdx.x;
    bx = (id >> 3) & 3;
    by = ((id >> 5) << 3) | (id & 7);
  } else {
    bx = blockIdx.x; by = blockIdx.y;
  }
  const int row0 = by * 64, col0 = bx * 128;
  const short* Ag = (const short*)A + (size_t)(row0 + lane) * K + w * 8;
  const short* Bg = (const short*)Bt + (size_t)(col0 + lane) * K + w * 8;
  floatx4 acc[2][4] = {};
  const int sA = (w * 64) * 8;
  const int sB = 2048 + (w * 128) * 8;
  {
    short* base = &lds[0];
    gload16(Ag, base + sA);
    gload16(Bg, base + sB);
    gload16(Bg + (size_t)64 * K, base + sB + 512);
  }
  const int nk = K >> 5;
  for (int i = 0; i < nk; ++i) {
    __syncthreads();
    if (i + 1 < nk) {
      const int k0 = (i + 1) << 5;
      short* base = &lds[((i + 1) & 1) * 6144];
      gload16(Ag + k0, base + sA);
      gload16(Bg + k0, base + sB);
      gload16(Bg + k0 + (size_t)64 * K, base + sB + 512);
    }
    const short* cur = &lds[(i & 1) * 6144];
    short8 af[2], bfr[4];
#pragma unroll
    for (int mt = 0; mt < 2; ++mt)
      af[mt] = *(const short8*)&cur[(quad * 64 + wm * 32 + mt * 16 + l16) * 8];
#pragma unroll
    for (int nt = 0; nt < 4; ++nt)
      bfr[nt] = *(const short8*)&cur[2048 + (quad * 128 + wn * 64 + nt * 16 + l16) * 8];
#pragma unroll
    for (int mt = 0; mt < 2; ++mt)
#pragma unroll
      for (int nt = 0; nt < 4; ++nt)
        acc[mt][nt] = __builtin_amdgcn_mfma_f32_16x16x32_bf16(af[mt], bfr[nt], acc[mt][nt], 0, 0, 0);
  }
  const int mb = row0 + wm * 32 + quad * 4;
  const int nb = col0 + wn * 64 + l16;
#pragma unroll
  for (int mt = 0; mt < 2; ++mt) {
#pragma unroll
    for (int nt = 0; nt < 4; ++nt) {
      floatx4 a4 = acc[mt][nt];
#pragma unroll
      for (int r = 0; r < 4; ++r) {
        int row = mb + mt * 16 + r;
        int col = nb + nt * 16;
        float val = a4[r];
        if (bias) val += bias[col];
        if (dogelu) val = 0.5f * val * (1.f + erff(val * 0.7071067811865475f));
        size_t idx = (size_t)row * N + col;
        if (resid) val += resid[idx];
        if (outF) outF[idx] = val;
        else outB[idx] = f2bf(val);
      }
    }
  }
}

// ---------------- MFMA flash attention ----------------
__global__ __launch_bounds__(256) void k_attn(const ushort_t* __restrict__ qkv,
                                              const int* __restrict__ lengths,
                                              ushort_t* __restrict__ o) {
  __shared__ ushort_t Ks[64 * 72];
  __shared__ ushort_t Vt[64 * 72];
  __shared__ ushort_t Ps[4][16 * 72];
  const int tid = threadIdx.x;
  const int w = tid >> 6, lane = tid & 63;
  const int quad = lane >> 4, l16 = lane & 15;
  const int tile = blockIdx.x & 15;
  const int bh = blockIdx.x >> 4;
  const int b = bh >> 3, h = bh & 7;
  const int len = lengths[b];
  const int tqa = tile * 64 + w * 16 + l16;
  const ushort_t* qp = qkv + ((size_t)(b * TT + tqa)) * 1536 + h * HSZ + quad * 8;
  short8 qf0 = *(const short8*)qp;
  short8 qf1 = *(const short8*)(qp + 32);
  floatx4 oacc[4] = {};
  float mrun[4], lrun[4];
#pragma unroll
  for (int r = 0; r < 4; ++r) { mrun[r] = -1e30f; lrun[r] = 0.f; }
  const int skey = tid >> 2, sseg = (tid & 3) << 4;
  const int vkp = (tid & 31) << 1, vds = (tid >> 5) << 3;
  const int nkt = (len + 63) >> 6;
  for (int kt = 0; kt < nkt; ++kt) {
    const int s0 = kt * 64;
    __syncthreads();
    {
      const ushort_t* kp = qkv + ((size_t)(b * TT + s0 + skey)) * 1536 + 512 + h * HSZ + sseg;
      short8 k0 = *(const short8*)kp;
      short8 k1 = *(const short8*)(kp + 8);
      *(short8*)&Ks[skey * 72 + sseg] = k0;
      *(short8*)&Ks[skey * 72 + sseg + 8] = k1;
      const ushort_t* vp0 = qkv + ((size_t)(b * TT + s0 + vkp)) * 1536 + 1024 + h * HSZ + vds;
      short8 v0 = *(const short8*)vp0;
      short8 v1 = *(const short8*)(vp0 + 1536);
#pragma unroll
      for (int i = 0; i < 8; ++i) {
        ushort2 pr;
        pr.x = (ushort_t)v0[i];
        pr.y = (ushort_t)v1[i];
        *(ushort2*)&Vt[(vds + i) * 72 + vkp] = pr;
      }
    }
    __syncthreads();
    floatx4 sacc[4] = {};
#pragma unroll
    for (int nt = 0; nt < 4; ++nt) {
      short8 kf0 = *(const short8*)&Ks[(nt * 16 + l16) * 72 + quad * 8];
      short8 kf1 = *(const short8*)&Ks[(nt * 16 + l16) * 72 + 32 + quad * 8];
      sacc[nt] = __builtin_amdgcn_mfma_f32_16x16x32_bf16(qf0, kf0, sacc[nt], 0, 0, 0);
      sacc[nt] = __builtin_amdgcn_mfma_f32_16x16x32_bf16(qf1, kf1, sacc[nt], 0, 0, 0);
    }
    float p[4][4], mx[4];
#pragma unroll
    for (int r = 0; r < 4; ++r) {
      float m = -1e30f;
#pragma unroll
      for (int nt = 0; nt < 4; ++nt) {
        float s = (s0 + nt * 16 + l16 < len) ? sacc[nt][r] * 0.125f : -1e30f;
        p[nt][r] = s;
        m = fmaxf(m, s);
      }
      mx[r] = m;
    }
#pragma unroll
    for (int off = 1; off < 16; off <<= 1) {
#pragma unroll
      for (int r = 0; r < 4; ++r) mx[r] = fmaxf(mx[r], __shfl_xor(mx[r], off, 64));
    }
    float corr[4], rs[4];
#pragma unroll
    for (int r = 0; r < 4; ++r) {
      float mnew = fmaxf(mrun[r], mx[r]);
      corr[r] = __expf(mrun[r] - mnew);
      mrun[r] = mnew;
      float s = 0.f;
#pragma unroll
      for (int nt = 0; nt < 4; ++nt) {
        float e = __expf(p[nt][r] - mnew);
        p[nt][r] = e;
        s += e;
      }
      rs[r] = s;
    }
#pragma unroll
    for (int off = 1; off < 16; off <<= 1) {
#pragma unroll
      for (int r = 0; r < 4; ++r) rs[r] += __shfl_xor(rs[r], off, 64);
    }
#pragma unroll
    for (int r = 0; r < 4; ++r) {
      lrun[r] = lrun[r] * corr[r] + rs[r];
#pragma unroll
      for (int nt = 0; nt < 4; ++nt) {
        oacc[nt][r] *= corr[r];
        Ps[w][(quad * 4 + r) * 72 + nt * 16 + l16] = f2bf(p[nt][r]);
      }
    }
    short8 pf0 = *(const short8*)&Ps[w][l16 * 72 + quad * 8];
    short8 pf1 = *(const short8*)&Ps[w][l16 * 72 + 32 + quad * 8];
#pragma unroll
    for (int nt = 0; nt < 4; ++nt) {
      short8 vf0 = *(const short8*)&Vt[(nt * 16 + l16) * 72 + quad * 8];
      short8 vf1 = *(const short8*)&Vt[(nt * 16 + l16) * 72 + 32 + quad * 8];
      oacc[nt] = __builtin_amdgcn_mfma_f32_16x16x32_bf16(pf0, vf0, oacc[nt], 0, 0, 0);
      oacc[nt] = __builtin_amdgcn_mfma_f32_16x16x32_bf16(pf1, vf1, oacc[nt], 0, 0, 0);
    }
  }
#pragma unroll
  for (int r = 0; r < 4; ++r) {
    int t = tile * 64 + w * 16 + quad * 4 + r;
    float inv = (t < len) ? 1.f / lrun[r] : 0.f;
    ushort_t* op = o + ((size_t)(b * TT + t)) * DD + h * HSZ + l16;
#pragma unroll
    for (int nt = 0; nt < 4; ++nt) op[nt * 16] = f2bf(oacc[nt][r] * inv);
  }
}

// ---------------- pool softmax: scores -> weights (per batch) ----------------
__global__ __launch_bounds__(256) void k_softw(const float* __restrict__ scores,
                                               const int* __restrict__ lengths,
                                               float* __restrict__ wts) {
  __shared__ float red[8];
  int tid = threadIdx.x, b = blockIdx.x;
  int len = lengths[b];
  const float* sb = scores + b * TT;
  float m = -1e30f;
  for (int t = tid; t < len; t += 256) m = fmaxf(m, sb[t]);
#pragma unroll
  for (int off = 32; off; off >>= 1) m = fmaxf(m, __shfl_down(m, off, 64));
  if ((tid & 63) == 0) red[tid >> 6] = m;
  __syncthreads();
  m = fmaxf(fmaxf(red[0], red[1]), fmaxf(red[2], red[3]));
  float ssum = 0.f;
  for (int t = tid; t < len; t += 256) ssum += __expf(sb[t] - m);
#pragma unroll
  for (int off = 32; off; off >>= 1) ssum += __shfl_down(ssum, off, 64);
  if ((tid & 63) == 0) red[4 + (tid >> 6)] = ssum;
  __syncthreads();
  float inv = 1.f / (red[4] + red[5] + red[6] + red[7]);
  for (int t = tid; t < TT; t += 256)
    wts[b * TT + t] = (t < len) ? __expf(sb[t] - m) * inv : 0.f;
}

// ---------------- weighted sum partials: grid (B, 16), 64 rows each ----------------
__global__ __launch_bounds__(256) void k_wsum(const float* __restrict__ xf,
                                              const float* __restrict__ wts,
                                              float* __restrict__ partial) {
  int b = blockIdx.x, c = blockIdx.y, tid = threadIdx.x;
  const float* xb = xf + ((size_t)b * TT + c * 64) * DD;
  const float* wb = wts + b * TT + c * 64;
  float a0 = 0.f, a1 = 0.f;
  for (int t = 0; t < 64; ++t) {
    float wv = wb[t];
    a0 += wv * xb[(size_t)t * DD + tid];
    a1 += wv * xb[(size_t)t * DD + tid + 256];
  }
  float* pp = partial + ((size_t)b * 16 + c) * DD;
  pp[tid] = a0;
  pp[tid + 256] = a1;
}

// ---------------- classification head (reduces the 16 partials) ----------------
__global__ __launch_bounds__(64) void k_head(const float* __restrict__ partial,
                                             const float* __restrict__ head_w,
                                             const float* __restrict__ head_b,
                                             float* __restrict__ out) {
  __shared__ float ssum[DD];
  int b = blockIdx.x, tid = threadIdx.x;
  for (int d = tid; d < DD; d += 64) {
    float s = 0.f;
#pragma unroll
    for (int c = 0; c < 16; ++c) s += partial[((size_t)b * 16 + c) * DD + d];
    ssum[d] = s;
  }
  __syncthreads();
  if (tid < 49) {
    float s = head_b[tid];
    for (int d = 0; d < DD; ++d) s += ssum[d] * head_w[d * 49 + tid];
    out[b * 49 + tid] = s;
  }
}

extern "C" void kernel_launch(void* const* d_in, const int* in_sizes, int n_in,
                              void* d_out, int out_size, void* d_ws, size_t ws_size,
                              hipStream_t stream) {
  const int* code = (const int*)d_in[0];
  const int* lengths = (const int*)d_in[1];
  const float* emb = (const float*)d_in[2];
  const float* Wq = (const float*)d_in[3];
  const float* Wk = (const float*)d_in[4];
  const float* Wv = (const float*)d_in[5];
  const float* Wo = (const float*)d_in[6];
  const float* bo = (const float*)d_in[7];
  const float* W1 = (const float*)d_in[8];
  const float* b1 = (const float*)d_in[9];
  const float* W2 = (const float*)d_in[10];
  const float* b2 = (const float*)d_in[11];
  const float* ln1_g = (const float*)d_in[12];
  const float* ln1_b = (const float*)d_in[13];
  const float* ln2_g = (const float*)d_in[14];
  const float* ln2_b = (const float*)d_in[15];
  const float* lnf_g = (const float*)d_in[16];
  const float* lnf_b = (const float*)d_in[17];
  const float* attn_w = (const float*)d_in[18];
  const float* attn_b = (const float*)d_in[19];
  const float* head_w = (const float*)d_in[20];
  const float* head_b = (const float*)d_in[21];
  float* out = (float*)d_out;

  const size_t NTOK = (size_t)BB * TT;  // 8192
  float* x = (float*)d_ws;                       // 8192*512 fp32
  ushort_t* xn = (ushort_t*)(x + NTOK * DD);     // 8192*512 bf16
  ushort_t* un = xn + NTOK * DD;                 // union: qkv | h1 | xf
  ushort_t* qkv = un;
  ushort_t* h1 = un;
  float* xf = (float*)un;
  ushort_t* wqt = un + (size_t)NTOK * FF4;
  ushort_t* wot = wqt + (size_t)LL * 1536 * 512;
  ushort_t* w1t = wot + (size_t)LL * 512 * 512;
  ushort_t* w2t = w1t + (size_t)LL * 512 * FF4;
  float* scores = (float*)(w2t + (size_t)LL * FF4 * 512);  // 8192
  float* wts = scores + NTOK;                              // 8192
  float* partial = wts + NTOK;                             // 8*16*512

  k_transpose<<<dim3(8, 1, 48), 256, 0, stream>>>(Wq, wqt,             64, (long)512 * 64, 8, (long)1536 * 512, (long)64 * 512, 512);
  k_transpose<<<dim3(8, 1, 48), 256, 0, stream>>>(Wk, wqt + 512 * 512,  64, (long)512 * 64, 8, (long)1536 * 512, (long)64 * 512, 512);
  k_transpose<<<dim3(8, 1, 48), 256, 0, stream>>>(Wv, wqt + 1024 * 512, 64, (long)512 * 64, 8, (long)1536 * 512, (long)64 * 512, 512);
  k_transpose<<<dim3(8, 8, 6), 256, 0, stream>>>(Wo, wot, 512, (long)512 * 512, 1, (long)512 * 512, 0, 512);
  k_transpose<<<dim3(8, 32, 6), 256, 0, stream>>>(W1, w1t, 2048, (long)512 * 2048, 1, (long)2048 * 512, 0, 512);
  k_transpose<<<dim3(32, 8, 6), 256, 0, stream>>>(W2, w2t, 512, (long)2048 * 512, 1, (long)512 * 2048, 0, 2048);

  k_embed<<<dim3((unsigned)((NTOK * DD) / 256)), dim3(256), 0, stream>>>(code, emb, x);

  for (int l = 0; l < LL; ++l) {
    k_ln<<<dim3(NTOK / 4), 256, 0, stream>>>(x, xn, nullptr, ln1_g + l * DD, ln1_b + l * DD,
                                             nullptr, nullptr, nullptr);
    k_gemm<<<dim3(12, 64), 256, 0, stream>>>(xn, wqt + (size_t)l * 1536 * 512, nullptr, nullptr,
                                             nullptr, qkv, (int)NTOK, 1536, 512, 0);
    k_attn<<<dim3(BB * HH * (TT / 64)), 256, 0, stream>>>(qkv, lengths, xn);
    k_gemm64<<<dim3(4, 128), 256, 0, stream>>>(xn, wot + (size_t)l * 512 * 512, x, bo + l * DD,
                                               x, nullptr, (int)NTOK, 512, 512, 0);
    k_ln<<<dim3(NTOK / 4), 256, 0, stream>>>(x, xn, nullptr, ln2_g + l * DD, ln2_b + l * DD,
                                             nullptr, nullptr, nullptr);
    k_gemm<<<dim3(16, 64), 256, 0, stream>>>(xn, w1t + (size_t)l * 512 * FF4, nullptr, b1 + l * FF4,
                                             nullptr, h1, (int)NTOK, FF4, 512, 1);
    k_gemm64<<<dim3(4, 128), 256, 0, stream>>>(h1, w2t + (size_t)l * FF4 * 512, x, b2 + l * DD,
                                               x, nullptr, (int)NTOK, 512, FF4, 0);
  }
  k_ln<<<dim3(NTOK / 4), 256, 0, stream>>>(x, nullptr, xf, lnf_g, lnf_b,
                                           attn_w, attn_b, scores);
  k_softw<<<dim3(BB), 256, 0, stream>>>(scores, lengths, wts);
  k_wsum<<<dim3(BB, 16), 256, 0, stream>>>(xf, wts, partial);
  k_head<<<dim3(BB), 64, 0, stream>>>(partial, head_w, head_b, out);
}